// Round 9
// baseline (480.062 us; speedup 1.0000x reference)
//
#include <hip/hip_runtime.h>

#define NYTOT 16384
#define NXP 4096
#define MTOT 65536   // B * NY
#define CYC 128
#define CXC 256
#define DIMC 384

typedef __attribute__((ext_vector_type(8))) _Float16 half8;
typedef __attribute__((ext_vector_type(4))) _Float16 half4;
typedef __attribute__((ext_vector_type(4))) float floatx4;
typedef __attribute__((ext_vector_type(2))) float floatx2;
typedef unsigned long long u64c;

using half_t = _Float16;

struct alignas(16) HF8 { half_t h[8]; };

__device__ __forceinline__ float fmed3(float a, float b, float c) {
  return __builtin_amdgcn_fmed3f(a, b, c);
}

// ---- packed fp32 helpers (VOP3P; HW-verified correct in round 6) --------
__device__ __forceinline__ floatx2 pkmul_sv(u64c s, floatx2 v) {
  floatx2 r; asm("v_pk_mul_f32 %0, %1, %2" : "=v"(r) : "s"(s), "v"(v)); return r;
}
__device__ __forceinline__ floatx2 pkadd_sv(u64c s, floatx2 v) {
  floatx2 r; asm("v_pk_add_f32 %0, %1, %2" : "=v"(r) : "s"(s), "v"(v)); return r;
}
__device__ __forceinline__ floatx2 pkmul_vv(floatx2 a, floatx2 b) {
  floatx2 r; asm("v_pk_mul_f32 %0, %1, %2" : "=v"(r) : "v"(a), "v"(b)); return r;
}
__device__ __forceinline__ floatx2 pkadd_vv(floatx2 a, floatx2 b) {
  floatx2 r; asm("v_pk_add_f32 %0, %1, %2" : "=v"(r) : "v"(a), "v"(b)); return r;
}
__device__ __forceinline__ u64c dup_sgpr(float v) {
  unsigned b = __float_as_uint(v);           // SALU shift/or (parallel pipe)
  return ((u64c)b << 32) | (u64c)b;
}
// d = (SY + pw) + (-2)*((Y0*px + Y1*py) + Y2*pz)
// Bitwise == ref's (SY+sx) - 2*inner, left-assoc (round-6 HW-verified):
// mul commutative bitwise; (-2)*i == -(2*i) bitwise; a + (-b) == a - b.
__device__ __forceinline__ floatx2 pkdist4(float4 p, floatx2 y0, floatx2 y1,
                                           floatx2 y2, floatx2 sy, floatx2 m2) {
  u64c px = dup_sgpr(p.x), py = dup_sgpr(p.y);
  u64c pz = dup_sgpr(p.z), pw = dup_sgpr(p.w);
  floatx2 t0 = pkmul_sv(px, y0);
  floatx2 t1 = pkmul_sv(py, y1);
  floatx2 s01 = pkadd_vv(t0, t1);
  floatx2 t2 = pkmul_sv(pz, y2);
  floatx2 inner = pkadd_vv(s01, t2);
  floatx2 u = pkadd_sv(pw, sy);
  floatx2 w = pkmul_vv(inner, m2);
  return pkadd_vv(u, w);
}

// ---------------- K0: merged prep — xq table + fp32->fp16 weights --------
// blocks 0..63: xq[b][j] = {x0,x1,x2,sx} (ref-order sx).
// blocks 64..415: W1/W2/W3 fp32->fp16 RNE into d_out scratch.
__global__ __launch_bounds__(256) void prep_kernel(
    const float* __restrict__ x_points, float4* __restrict__ xq,
    const float* __restrict__ W1, const float* __restrict__ W2,
    const float* __restrict__ W3, half_t* __restrict__ wout) {
#pragma clang fp contract(off)
  const int bid = blockIdx.x;
  if (bid < 64) {
    int j = bid * 256 + threadIdx.x;          // 0..16383
    int b = j >> 12, jj = j & 4095;
    const float* p = x_points + (size_t)b * NXP * 3 + 3 * jj;
    float x0 = p[0], x1 = p[1], x2 = p[2];
    float sx = (x0 * x0 + x1 * x1) + x2 * x2; // ref order
    float4 v; v.x = x0; v.y = x1; v.z = x2; v.w = sx;
    xq[j] = v;
  } else {
    int i = (bid - 64) * 256 + threadIdx.x;   // float4 index, 0..90111
    const float* src; half_t* dst; int j;
    if (i < 49152)      { src = W1; dst = wout;          j = i; }
    else if (i < 81920) { src = W2; dst = wout + 196608; j = i - 49152; }
    else                { src = W3; dst = wout + 327680; j = i - 81920; }
    floatx4 v = ((const floatx4*)src)[j];
    half4 h;
#pragma unroll
    for (int e = 0; e < 4; ++e) h[e] = (half_t)v[e];
    ((half4*)dst)[j] = h;
  }
}

// ---------------- K1: 3-NN interpolation + concat -> A0 fp16 [M, 384] ----
// Round-5 verified structure; ONLY the 2-line distance expression replaced
// by explicit v_pk_f32 asm (bit-identical values). Everything else (loads,
// med3 chains, gating, merges, gather) byte-identical to round 5.
__global__ __launch_bounds__(1024, 8) void interp_kernel(
    const float* __restrict__ y_points, const float* __restrict__ y_feats,
    const float* __restrict__ x_feats, const float4* __restrict__ xq,
    half_t* __restrict__ A0) {
#pragma clang fp contract(off)
  __shared__ float pd[16][128][3];        // 24 KB partial dists
  __shared__ int   pi[16][128][3];        // 24 KB partial idx
  __shared__ float t2s[128];              // 0.5 KB global 3rd-smallest
  __shared__ float sw[3][128];            // 1.5 KB final weights
  __shared__ int   si[3][128];            // 1.5 KB final idx
  const int b = blockIdx.x >> 7;
  const int chunk = blockIdx.x & 127;
  const int t = threadIdx.x;
  const int lane = t & 63;
  const int seg = t >> 6;                 // wave id == segment, 0..15
  const int yloc = lane << 1;             // my 2 y's: yloc, yloc+1

  // y coords for the pair (rows are consecutive)
  const float* yp = y_points + ((size_t)b * NYTOT + chunk * 128 + yloc) * 3;
  floatx2 Y0 = {yp[0], yp[3]};
  floatx2 Y1 = {yp[1], yp[4]};
  floatx2 Y2 = {yp[2], yp[5]};
  floatx2 SY = (Y0 * Y0 + Y1 * Y1) + Y2 * Y2;       // ref order per element
  const floatx2 M2 = {-2.0f, -2.0f};

  const float4* xqs = xq + (size_t)b * NXP;
  const int jb = __builtin_amdgcn_readfirstlane(seg * 256);

  // ---- phase 1: value-only top-3 per (seg, y) via med3/min ----
  floatx2 D0 = {1e30f, 1e30f}, D1 = D0, D2 = D0;
#pragma unroll 8
  for (int jj = 0; jj < 256; ++jj) {
    float4 p = xqs[jb + jj];                        // wave-uniform load
    floatx2 d = pkdist4(p, Y0, Y1, Y2, SY, M2);
    D2.x = fmed3(d.x, D1.x, D2.x);  D2.y = fmed3(d.y, D1.y, D2.y);
    D1.x = fmed3(d.x, D0.x, D1.x);  D1.y = fmed3(d.y, D0.y, D1.y);
    D0.x = fminf(d.x, D0.x);        D0.y = fminf(d.y, D0.y);
  }
  pd[seg][yloc][0] = D0.x; pd[seg][yloc][1] = D1.x; pd[seg][yloc][2] = D2.x;
  pd[seg][yloc + 1][0] = D0.y; pd[seg][yloc + 1][1] = D1.y; pd[seg][yloc + 1][2] = D2.y;
  __syncthreads();

  // global 3rd-smallest per y
  if (t < 128) {
    float m0 = 1e30f, m1 = 1e30f, m2 = 1e30f;
#pragma unroll
    for (int s = 0; s < 16; ++s)
#pragma unroll
      for (int c = 0; c < 3; ++c) {
        float v = pd[s][t][c];
        m2 = fmed3(v, m1, m2);
        m1 = fmed3(v, m0, m1);
        m0 = fminf(v, m0);
      }
    t2s[t] = m2;
  }
  __syncthreads();

  // ---- phase 2: gated stable index recovery ----
  const float t2a = t2s[yloc], t2b = t2s[yloc + 1];
  const float tmax = fmaxf(t2a, t2b);
  float e0a = 1e30f, e1a = 1e30f, e2a = 1e30f; int k0a = 0, k1a = 0, k2a = 0;
  float e0b = 1e30f, e1b = 1e30f, e2b = 1e30f; int k0b = 0, k1b = 0, k2b = 0;
#pragma unroll 4
  for (int jj = 0; jj < 256; ++jj) {
    float4 p = xqs[jb + jj];
    floatx2 d = pkdist4(p, Y0, Y1, Y2, SY, M2);
    if (fminf(d.x, d.y) <= tmax) {                  // rare
      int j = jb + jj;
      {
        float dv = d.x;
        bool l0 = dv < e0a, l1 = dv < e1a, l2 = dv < e2a;
        e2a = l1 ? e1a : (l2 ? dv : e2a);  k2a = l1 ? k1a : (l2 ? j : k2a);
        e1a = l0 ? e0a : (l1 ? dv : e1a);  k1a = l0 ? k0a : (l1 ? j : k1a);
        e0a = l0 ? dv : e0a;               k0a = l0 ? j : k0a;
      }
      {
        float dv = d.y;
        bool l0 = dv < e0b, l1 = dv < e1b, l2 = dv < e2b;
        e2b = l1 ? e1b : (l2 ? dv : e2b);  k2b = l1 ? k1b : (l2 ? j : k2b);
        e1b = l0 ? e0b : (l1 ? dv : e1b);  k1b = l0 ? k0b : (l1 ? j : k1b);
        e0b = l0 ? dv : e0b;               k0b = l0 ? j : k0b;
      }
    }
  }
  pd[seg][yloc][0] = e0a; pd[seg][yloc][1] = e1a; pd[seg][yloc][2] = e2a;
  pi[seg][yloc][0] = k0a; pi[seg][yloc][1] = k1a; pi[seg][yloc][2] = k2a;
  pd[seg][yloc + 1][0] = e0b; pd[seg][yloc + 1][1] = e1b; pd[seg][yloc + 1][2] = e2b;
  pi[seg][yloc + 1][0] = k0b; pi[seg][yloc + 1][1] = k1b; pi[seg][yloc + 1][2] = k2b;
  __syncthreads();

  // 48-way stable merge (seg-ascending) + weights
  if (t < 128) {
    float f0 = 1e30f, f1 = 1e30f, f2 = 1e30f;
    int m0i = 0, m1i = 0, m2i = 0;
#pragma unroll
    for (int s = 0; s < 16; ++s)
#pragma unroll
      for (int c = 0; c < 3; ++c) {
        float d = pd[s][t][c]; int j = pi[s][t][c];
        bool l0 = d < f0, l1 = d < f1, l2 = d < f2;
        f2 = l1 ? f1 : (l2 ? d : f2);  m2i = l1 ? m1i : (l2 ? j : m2i);
        f1 = l0 ? f0 : (l1 ? d : f1);  m1i = l0 ? m0i : (l1 ? j : m1i);
        f0 = l0 ? d : f0;              m0i = l0 ? j : m0i;
      }
    float w0 = 1.0f / (f0 + 1e-8f), w1 = 1.0f / (f1 + 1e-8f), w2 = 1.0f / (f2 + 1e-8f);
    float ws = (w0 + w1) + w2;
    sw[0][t] = w0 / ws; sw[1][t] = w1 / ws; sw[2][t] = w2 / ws;
    si[0][t] = m0i; si[1][t] = m1i; si[2][t] = m2i;
  }
  __syncthreads();

  // ---- gather: vectorized float4 rows (row index wave-uniform -> 1KB loads)
  const floatx4* xf4 = (const floatx4*)(x_feats + (size_t)b * NXP * CXC);
  const floatx4* yf4 = (const floatx4*)(y_feats + ((size_t)b * NYTOT + chunk * 128) * CYC);
  half_t* fb = A0 + ((size_t)b * NYTOT + chunk * 128) * DIMC;
  {
    const int q = t & 63;           // float4 index within 256-ch row
    const int ysub = t >> 6;        // 16 y-groups
    for (int y2 = ysub; y2 < 128; y2 += 16) {
      int j0 = si[0][y2], j1 = si[1][y2], j2 = si[2][y2];
      float a0 = sw[0][y2], a1 = sw[1][y2], a2 = sw[2][y2];
      floatx4 v0 = xf4[(size_t)j0 * 64 + q];
      floatx4 v1 = xf4[(size_t)j1 * 64 + q];
      floatx4 v2 = xf4[(size_t)j2 * 64 + q];
      half4 h;
#pragma unroll
      for (int e = 0; e < 4; ++e)
        h[e] = (half_t)fmaf(v2[e], a2, fmaf(v1[e], a1, v0[e] * a0));
      *(half4*)&fb[(size_t)y2 * DIMC + CYC + q * 4] = h;
    }
  }
  {
    const int q2 = t & 31;          // float4 index within 128-ch row
    const int ysub2 = t >> 5;       // 32 y-groups
    for (int y2 = ysub2; y2 < 128; y2 += 32) {
      floatx4 v = yf4[(size_t)y2 * 32 + q2];
      half4 h;
#pragma unroll
      for (int e = 0; e < 4; ++e) h[e] = (half_t)v[e];
      *(half4*)&fb[(size_t)y2 * DIMC + q2 * 4] = h;
    }
  }
}

// ---------------- GEMM 256x128 (round-5 verified; best measured config) --
// 256x128 M*N tile, BK=64, 512 thr (8 waves, 4Mx2N), mfma_f32_16x16x32_f16.
// 1D grid, n-fastest decode + bijective XCD-chunk swizzle.
template<int K, int O, int NTN, bool FUSEA>
__global__ __launch_bounds__(512) void gemm256(
    const half_t* __restrict__ A, const half_t* __restrict__ Wh,
    const float* __restrict__ bias, half_t* __restrict__ C,
    float* __restrict__ sums, const float* __restrict__ ssA) {
  __shared__ __align__(16) short As[16][2][512];  // 32 KB
  __shared__ __align__(16) short Bs[8][2][512];   // 16 KB
  constexpr int NWG = (MTOT / 256) * NTN;         // multiple of 8
  const int lin = (blockIdx.x & 7) * (NWG >> 3) + (blockIdx.x >> 3);
  const int m0 = (lin / NTN) * 256;
  const int n0 = (lin % NTN) * 128;
  const int tid = threadIdx.x;
  const int lane = tid & 63;
  const int wid = tid >> 6;            // 0..7
  const int wm = wid >> 1, wn = wid & 1;
  const int lm = lane & 15;
  const int lk = (lane >> 4) * 8;
  floatx4 acc[4][4] = {};

  for (int k0 = 0; k0 < K; k0 += 64) {
    __syncthreads();
    if constexpr (FUSEA) {
#pragma unroll
      for (int c = 0; c < 2; ++c) {
        int id = wid * 2 + c;          // 0..15 (wave-uniform)
        int sub = id >> 1, ks = id & 1;
        const half_t* src = Wh + (size_t)(n0 + sub * 16 + lm) * K + (k0 + ks * 32 + lk);
        __builtin_amdgcn_global_load_lds(
            (const __attribute__((address_space(1))) void*)src,
            (__attribute__((address_space(3))) void*)&Bs[sub][ks][0], 16, 0, 0);
      }
      const int r = tid & 255;
      const int hh = tid >> 8;
      const half_t* arow = A + (size_t)(m0 + r) * K + k0 + hh * 32;
      half8 in[4];
#pragma unroll
      for (int g = 0; g < 4; ++g) in[g] = *(const half8*)&arow[g * 8];
#pragma unroll
      for (int g = 0; g < 4; ++g) {
        int kc = k0 + hh * 32 + g * 8;
        half8 h;
#pragma unroll
        for (int e = 0; e < 8; ++e) {
          float f = fmaxf((float)in[g][e] * ssA[kc + e] + ssA[K + kc + e], 0.f);
          h[e] = (half_t)f;
        }
        *(half8*)&As[r >> 4][hh][(g * 16 + (r & 15)) * 8] = h;
      }
    } else {
#pragma unroll
      for (int c = 0; c < 6; ++c) {
        int id = wid * 6 + c;          // 0..47
        if (id < 32) {
          int sub = id >> 1, ks = id & 1;
          const half_t* src = A + (size_t)(m0 + sub * 16 + lm) * K + (k0 + ks * 32 + lk);
          __builtin_amdgcn_global_load_lds(
              (const __attribute__((address_space(1))) void*)src,
              (__attribute__((address_space(3))) void*)&As[sub][ks][0], 16, 0, 0);
        } else {
          int id2 = id - 32;
          int sub = id2 >> 1, ks = id2 & 1;
          const half_t* src = Wh + (size_t)(n0 + sub * 16 + lm) * K + (k0 + ks * 32 + lk);
          __builtin_amdgcn_global_load_lds(
              (const __attribute__((address_space(1))) void*)src,
              (__attribute__((address_space(3))) void*)&Bs[sub][ks][0], 16, 0, 0);
        }
      }
    }
    __syncthreads();
#pragma unroll
    for (int ks = 0; ks < 2; ++ks) {
      half8 af[4], bfm[4];
#pragma unroll
      for (int i = 0; i < 4; ++i) af[i] = *(const half8*)&As[wm * 4 + i][ks][lane * 8];
#pragma unroll
      for (int j = 0; j < 4; ++j) bfm[j] = *(const half8*)&Bs[wn * 4 + j][ks][lane * 8];
#pragma unroll
      for (int i = 0; i < 4; ++i)
#pragma unroll
        for (int j = 0; j < 4; ++j)
          acc[i][j] = __builtin_amdgcn_mfma_f32_16x16x32_f16(af[i], bfm[j], acc[i][j], 0, 0, 0);
    }
  }

  // epilogue: C/D layout col=lane&15, row=(lane>>4)*4+rr; fused BN stats
#pragma unroll
  for (int j = 0; j < 4; ++j) {
    int nn = n0 + wn * 64 + j * 16 + lm;
    float bv = bias[nn];
    float psum = 0.f, psq = 0.f;
#pragma unroll
    for (int i = 0; i < 4; ++i) {
      int mr = m0 + wm * 64 + i * 16 + (lane >> 4) * 4;
#pragma unroll
      for (int rr = 0; rr < 4; ++rr) {
        float z = acc[i][j][rr] + bv;
        C[(size_t)(mr + rr) * O + nn] = (half_t)z;
        psum += z; psq += z * z;
      }
    }
    psum += __shfl_xor(psum, 16, 64); psq += __shfl_xor(psq, 16, 64);
    psum += __shfl_xor(psum, 32, 64); psq += __shfl_xor(psq, 32, 64);
    if ((lane >> 4) == 0) {
      atomicAdd(&sums[nn], psum);
      atomicAdd(&sums[O + nn], psq);
    }
  }
}

// ---------------- GEMM 128x128 (verified; used for gemm3) ---------------
template<int K, int O, bool FUSEA>
__global__ __launch_bounds__(256) void gemm_f16(
    const half_t* __restrict__ A, const half_t* __restrict__ Wh,
    const float* __restrict__ bias, half_t* __restrict__ C,
    float* __restrict__ sums, const float* __restrict__ ssA) {
  __shared__ __align__(16) short As[8][2][512];   // [m_sub][k_sub][lane*8+e]
  __shared__ __align__(16) short Bs[8][2][512];
  const int m0 = blockIdx.x * 128;
  const int n0 = blockIdx.y * 128;
  const int tid = threadIdx.x;
  const int lane = tid & 63;
  const int wid = tid >> 6;
  const int wm = wid >> 1, wn = wid & 1;
  const int lm = lane & 15;
  const int lk = (lane >> 4) * 8;
  floatx4 acc[4][4] = {};

  for (int k0 = 0; k0 < K; k0 += 64) {
    __syncthreads();
    if constexpr (FUSEA) {
#pragma unroll
      for (int c = 0; c < 4; ++c) {
        int id = wid * 4 + c;          // 0..15
        int sub = id >> 1;
        int ks = id & 1;
        const half_t* src = Wh + (size_t)(n0 + sub * 16 + lm) * K + (k0 + ks * 32 + lk);
        __builtin_amdgcn_global_load_lds(
            (const __attribute__((address_space(1))) void*)src,
            (__attribute__((address_space(3))) void*)&Bs[sub][ks][0], 16, 0, 0);
      }
      const int r = tid & 127;
      const int hh = tid >> 7;
      const half_t* arow = A + (size_t)(m0 + r) * K + k0 + hh * 32;
      half8 in[4];
#pragma unroll
      for (int g = 0; g < 4; ++g) in[g] = *(const half8*)&arow[g * 8];
#pragma unroll
      for (int g = 0; g < 4; ++g) {
        int kc = k0 + hh * 32 + g * 8;
        half8 h;
#pragma unroll
        for (int e = 0; e < 8; ++e) {
          float f = fmaxf((float)in[g][e] * ssA[kc + e] + ssA[K + kc + e], 0.f);
          h[e] = (half_t)f;
        }
        *(half8*)&As[r >> 4][hh][(g * 16 + (r & 15)) * 8] = h;
      }
    } else {
#pragma unroll
      for (int c = 0; c < 8; ++c) {
        int id = wid * 8 + c;          // 0..31 (wave-uniform)
        int sub = (id >> 1) & 7;
        int ks = id & 1;
        const half_t* src = (id < 16)
            ? A  + (size_t)(m0 + sub * 16 + lm) * K + (k0 + ks * 32 + lk)
            : Wh + (size_t)(n0 + sub * 16 + lm) * K + (k0 + ks * 32 + lk);
        __builtin_amdgcn_global_load_lds(
            (const __attribute__((address_space(1))) void*)src,
            (__attribute__((address_space(3))) void*)(id < 16 ? &As[sub][ks][0]
                                                             : &Bs[sub][ks][0]),
            16, 0, 0);
      }
    }
    __syncthreads();
#pragma unroll
    for (int ks = 0; ks < 2; ++ks) {
      half8 af[4], bfm[4];
#pragma unroll
      for (int i = 0; i < 4; ++i) af[i] = *(const half8*)&As[wm * 4 + i][ks][lane * 8];
#pragma unroll
      for (int j = 0; j < 4; ++j) bfm[j] = *(const half8*)&Bs[wn * 4 + j][ks][lane * 8];
#pragma unroll
      for (int i = 0; i < 4; ++i)
#pragma unroll
        for (int j = 0; j < 4; ++j)
          acc[i][j] = __builtin_amdgcn_mfma_f32_16x16x32_f16(af[i], bfm[j], acc[i][j], 0, 0, 0);
    }
  }

#pragma unroll
  for (int j = 0; j < 4; ++j) {
    int nn = n0 + wn * 64 + j * 16 + lm;
    float bv = bias[nn];
    float psum = 0.f, psq = 0.f;
#pragma unroll
    for (int i = 0; i < 4; ++i) {
      int mr = m0 + wm * 64 + i * 16 + (lane >> 4) * 4;
#pragma unroll
      for (int rr = 0; rr < 4; ++rr) {
        float z = acc[i][j][rr] + bv;
        C[(size_t)(mr + rr) * O + nn] = (half_t)z;
        psum += z; psq += z * z;
      }
    }
    psum += __shfl_xor(psum, 16, 64); psq += __shfl_xor(psq, 16, 64);
    psum += __shfl_xor(psum, 32, 64); psq += __shfl_xor(psq, 32, 64);
    if ((lane >> 4) == 0) {
      atomicAdd(&sums[nn], psum);
      atomicAdd(&sums[O + nn], psq);
    }
  }
}

// ---------------- finalize BN scale/shift ----------
__global__ void finalize_kernel(const float* __restrict__ sums, const float* __restrict__ g,
                                const float* __restrict__ be, float* __restrict__ ss, int O) {
  int c = threadIdx.x;
  if (c < O) {
    const float invN = 1.0f / 65536.0f;
    float mean = sums[c] * invN;
    float var = sums[O + c] * invN - mean * mean;
    float sc = g[c] / sqrtf(var + 1e-5f);
    float sh = be[c] - mean * sc;
    if (!isfinite(sc) || !isfinite(sh)) { sc = 1.0f; sh = 0.0f; }
    ss[c] = sc;
    ss[O + c] = sh;
  }
}

// ---------------- layer3 BN + ReLU + transpose to [B, C, N] fp32 --------
__global__ __launch_bounds__(256) void bn_transpose_kernel(
    const half_t* __restrict__ Z3, const float* __restrict__ ss, float* __restrict__ out) {
  __shared__ float tile[64][129];
  const int r0 = blockIdx.x * 64;
  const int b = r0 >> 14;
  const int n0 = r0 & (NYTOT - 1);
  const int t = threadIdx.x;
  const int cl = t & 127, rl = t >> 7;      // 2 rows per pass
  for (int p = 0; p < 32; ++p) {
    int rr = p * 2 + rl;
    float v = (float)Z3[(size_t)(r0 + rr) * 128 + cl];
    tile[rr][cl] = fmaxf(v * ss[cl] + ss[128 + cl], 0.f);
  }
  __syncthreads();
  const int nl = t & 63, cj = t >> 6;       // 4 channels per pass
  for (int p = 0; p < 32; ++p) {
    int c = p * 4 + cj;
    out[(size_t)b * 128 * NYTOT + (size_t)c * NYTOT + n0 + nl] = tile[nl][c];
  }
}

extern "C" void kernel_launch(void* const* d_in, const int* in_sizes, int n_in,
                              void* d_out, int out_size, void* d_ws, size_t ws_size,
                              hipStream_t stream) {
  const float* y_points = (const float*)d_in[0];
  const float* y_feats  = (const float*)d_in[1];
  const float* x_points = (const float*)d_in[2];
  const float* x_feats  = (const float*)d_in[3];
  const float* W1 = (const float*)d_in[4];  const float* b1 = (const float*)d_in[5];
  const float* g1 = (const float*)d_in[6];  const float* be1 = (const float*)d_in[7];
  const float* W2 = (const float*)d_in[8];  const float* b2 = (const float*)d_in[9];
  const float* g2 = (const float*)d_in[10]; const float* be2 = (const float*)d_in[11];
  const float* W3 = (const float*)d_in[12]; const float* b3 = (const float*)d_in[13];
  const float* g3 = (const float*)d_in[14]; const float* be3 = (const float*)d_in[15];

  // workspace layout (peak unchanged):
  //   [0, 50.33MB)        : A0 fp16 [M,384]  (later aliased by z2)
  //   [50.33MB, 117.44MB) : z1 fp16 [M,512]  (xq table lives here pre-gemm1,
  //                         later aliased by z3)
  //   [117.44MB, ...)     : BN stats
  // d_out (33.5 MB) doubles as scratch for fp16 weights until bn_transpose.
  char* ws = (char*)d_ws;
  half_t* A0 = (half_t*)ws;                      // 65536*384*2 = 50,331,648
  half_t* z1 = (half_t*)(ws + 50331648);         // 65536*512*2 = 67,108,864
  half_t* z2 = (half_t*)ws;                      // alias A0 (dead after gemm1)
  half_t* z3 = (half_t*)(ws + 50331648);         // alias z1 (dead after gemm2)
  float4* xq = (float4*)(ws + 50331648);         // alias z1 head (dead before gemm1)
  float* st = (float*)(ws + 117440512);
  // st floats: sum1/sq1 @0 (1024), sum2/sq2 @1024 (512), sum3/sq3 @1536 (256),
  //            ss1 @1792 (1024), ss2 @2816 (512), ss3 @3328 (256)
  half_t* W1h = (half_t*)d_out;                  // 512*384  = 196608 halfs
  half_t* W2h = W1h + 196608;                    // 256*512  = 131072 halfs
  half_t* W3h = W1h + 327680;                    // 128*256  =  32768 halfs
  hipMemsetAsync(st, 0, 1792 * sizeof(float), stream);

  prep_kernel<<<416, 256, 0, stream>>>(x_points, xq, W1, W2, W3, W1h);
  interp_kernel<<<512, 1024, 0, stream>>>(y_points, y_feats, x_feats, xq, A0);

  // gemm1: 256x128 tile, 1024 blocks (XCD-swizzled, n-fastest)
  gemm256<384, 512, 4, false><<<1024, 512, 0, stream>>>(A0, W1h, b1, z1, st + 0, nullptr);
  finalize_kernel<<<1, 512, 0, stream>>>(st + 0, g1, be1, st + 1792, 512);

  // gemm2: 256x128 tile, BN1+ReLU fused into A-staging
  gemm256<512, 256, 2, true><<<512, 512, 0, stream>>>(z1, W2h, b2, z2, st + 1024, st + 1792);
  finalize_kernel<<<1, 256, 0, stream>>>(st + 1024, g2, be2, st + 2816, 256);

  // gemm3: 128x128 tile, BN2+ReLU fused into A-staging
  gemm_f16<256, 128, true><<<dim3(512, 1), 256, 0, stream>>>(z2, W3h, b3, z3, st + 1536, st + 2816);
  finalize_kernel<<<1, 128, 0, stream>>>(st + 1536, g3, be3, st + 3328, 128);

  // BN3+ReLU fused into the output transpose
  bn_transpose_kernel<<<1024, 256, 0, stream>>>(z3, st + 3328, (float*)d_out);
}

// Round 10
// 460.923 us; speedup vs baseline: 1.0415x; 1.0415x over previous
//
#include <hip/hip_runtime.h>

#define NYTOT 16384
#define NXP 4096
#define MTOT 65536   // B * NY
#define CYC 128
#define CXC 256
#define DIMC 384

typedef __attribute__((ext_vector_type(8))) _Float16 half8;
typedef __attribute__((ext_vector_type(4))) _Float16 half4;
typedef __attribute__((ext_vector_type(4))) float floatx4;
typedef __attribute__((ext_vector_type(2))) float floatx2;

using half_t = _Float16;

struct alignas(16) HF8 { half_t h[8]; };

__device__ __forceinline__ float fmed3(float a, float b, float c) {
  return __builtin_amdgcn_fmed3f(a, b, c);
}

// ---------------- K0: merged prep — xq table + fp32->fp16 weights --------
// blocks 0..63: xq[b][j] = {x0,x1,x2,sx} (ref-order sx).
// blocks 64..415: W1/W2/W3 fp32->fp16 RNE into d_out scratch.
__global__ __launch_bounds__(256) void prep_kernel(
    const float* __restrict__ x_points, float4* __restrict__ xq,
    const float* __restrict__ W1, const float* __restrict__ W2,
    const float* __restrict__ W3, half_t* __restrict__ wout) {
#pragma clang fp contract(off)
  const int bid = blockIdx.x;
  if (bid < 64) {
    int j = bid * 256 + threadIdx.x;          // 0..16383
    int b = j >> 12, jj = j & 4095;
    const float* p = x_points + (size_t)b * NXP * 3 + 3 * jj;
    float x0 = p[0], x1 = p[1], x2 = p[2];
    float sx = (x0 * x0 + x1 * x1) + x2 * x2; // ref order
    float4 v; v.x = x0; v.y = x1; v.z = x2; v.w = sx;
    xq[j] = v;
  } else {
    int i = (bid - 64) * 256 + threadIdx.x;   // float4 index, 0..90111
    const float* src; half_t* dst; int j;
    if (i < 49152)      { src = W1; dst = wout;          j = i; }
    else if (i < 81920) { src = W2; dst = wout + 196608; j = i - 49152; }
    else                { src = W3; dst = wout + 327680; j = i - 81920; }
    floatx4 v = ((const floatx4*)src)[j];
    half4 h;
#pragma unroll
    for (int e = 0; e < 4; ++e) h[e] = (half_t)v[e];
    ((half4*)dst)[j] = h;
  }
}

// ---------------- K1: 3-NN interpolation + concat -> A0 fp16 [M, 384] ----
// (exact round-5/8 verified version; compiler's floatx2 codegen beats both
// hand-SoA (r6) and inline pk-asm (r9) — keep as is)
__global__ __launch_bounds__(1024, 8) void interp_kernel(
    const float* __restrict__ y_points, const float* __restrict__ y_feats,
    const float* __restrict__ x_feats, const float4* __restrict__ xq,
    half_t* __restrict__ A0) {
#pragma clang fp contract(off)
  __shared__ float pd[16][128][3];        // 24 KB partial dists
  __shared__ int   pi[16][128][3];        // 24 KB partial idx
  __shared__ float t2s[128];              // 0.5 KB global 3rd-smallest
  __shared__ float sw[3][128];            // 1.5 KB final weights
  __shared__ int   si[3][128];            // 1.5 KB final idx
  const int b = blockIdx.x >> 7;
  const int chunk = blockIdx.x & 127;
  const int t = threadIdx.x;
  const int lane = t & 63;
  const int seg = t >> 6;                 // wave id == segment, 0..15
  const int yloc = lane << 1;             // my 2 y's: yloc, yloc+1

  // y coords for the pair (rows are consecutive)
  const float* yp = y_points + ((size_t)b * NYTOT + chunk * 128 + yloc) * 3;
  floatx2 Y0 = {yp[0], yp[3]};
  floatx2 Y1 = {yp[1], yp[4]};
  floatx2 Y2 = {yp[2], yp[5]};
  floatx2 SY = (Y0 * Y0 + Y1 * Y1) + Y2 * Y2;       // ref order per element

  const float4* xqs = xq + (size_t)b * NXP;
  const int jb = __builtin_amdgcn_readfirstlane(seg * 256);

  // ---- phase 1: value-only top-3 per (seg, y) via med3/min ----
  floatx2 D0 = {1e30f, 1e30f}, D1 = D0, D2 = D0;
#pragma unroll 8
  for (int jj = 0; jj < 256; ++jj) {
    float4 p = xqs[jb + jj];                        // wave-uniform load
    floatx2 inner = (Y0 * p.x + Y1 * p.y) + Y2 * p.z;
    floatx2 d = (SY + p.w) - 2.0f * inner;
    D2.x = fmed3(d.x, D1.x, D2.x);  D2.y = fmed3(d.y, D1.y, D2.y);
    D1.x = fmed3(d.x, D0.x, D1.x);  D1.y = fmed3(d.y, D0.y, D1.y);
    D0.x = fminf(d.x, D0.x);        D0.y = fminf(d.y, D0.y);
  }
  pd[seg][yloc][0] = D0.x; pd[seg][yloc][1] = D1.x; pd[seg][yloc][2] = D2.x;
  pd[seg][yloc + 1][0] = D0.y; pd[seg][yloc + 1][1] = D1.y; pd[seg][yloc + 1][2] = D2.y;
  __syncthreads();

  // global 3rd-smallest per y
  if (t < 128) {
    float m0 = 1e30f, m1 = 1e30f, m2 = 1e30f;
#pragma unroll
    for (int s = 0; s < 16; ++s)
#pragma unroll
      for (int c = 0; c < 3; ++c) {
        float v = pd[s][t][c];
        m2 = fmed3(v, m1, m2);
        m1 = fmed3(v, m0, m1);
        m0 = fminf(v, m0);
      }
    t2s[t] = m2;
  }
  __syncthreads();

  // ---- phase 2: gated stable index recovery ----
  const float t2a = t2s[yloc], t2b = t2s[yloc + 1];
  const float tmax = fmaxf(t2a, t2b);
  float e0a = 1e30f, e1a = 1e30f, e2a = 1e30f; int k0a = 0, k1a = 0, k2a = 0;
  float e0b = 1e30f, e1b = 1e30f, e2b = 1e30f; int k0b = 0, k1b = 0, k2b = 0;
#pragma unroll 4
  for (int jj = 0; jj < 256; ++jj) {
    float4 p = xqs[jb + jj];
    floatx2 inner = (Y0 * p.x + Y1 * p.y) + Y2 * p.z;
    floatx2 d = (SY + p.w) - 2.0f * inner;
    if (fminf(d.x, d.y) <= tmax) {                  // rare
      int j = jb + jj;
      {
        float dv = d.x;
        bool l0 = dv < e0a, l1 = dv < e1a, l2 = dv < e2a;
        e2a = l1 ? e1a : (l2 ? dv : e2a);  k2a = l1 ? k1a : (l2 ? j : k2a);
        e1a = l0 ? e0a : (l1 ? dv : e1a);  k1a = l0 ? k0a : (l1 ? j : k1a);
        e0a = l0 ? dv : e0a;               k0a = l0 ? j : k0a;
      }
      {
        float dv = d.y;
        bool l0 = dv < e0b, l1 = dv < e1b, l2 = dv < e2b;
        e2b = l1 ? e1b : (l2 ? dv : e2b);  k2b = l1 ? k1b : (l2 ? j : k2b);
        e1b = l0 ? e0b : (l1 ? dv : e1b);  k1b = l0 ? k0b : (l1 ? j : k1b);
        e0b = l0 ? dv : e0b;               k0b = l0 ? j : k0b;
      }
    }
  }
  pd[seg][yloc][0] = e0a; pd[seg][yloc][1] = e1a; pd[seg][yloc][2] = e2a;
  pi[seg][yloc][0] = k0a; pi[seg][yloc][1] = k1a; pi[seg][yloc][2] = k2a;
  pd[seg][yloc + 1][0] = e0b; pd[seg][yloc + 1][1] = e1b; pd[seg][yloc + 1][2] = e2b;
  pi[seg][yloc + 1][0] = k0b; pi[seg][yloc + 1][1] = k1b; pi[seg][yloc + 1][2] = k2b;
  __syncthreads();

  // 48-way stable merge (seg-ascending) + weights
  if (t < 128) {
    float f0 = 1e30f, f1 = 1e30f, f2 = 1e30f;
    int m0i = 0, m1i = 0, m2i = 0;
#pragma unroll
    for (int s = 0; s < 16; ++s)
#pragma unroll
      for (int c = 0; c < 3; ++c) {
        float d = pd[s][t][c]; int j = pi[s][t][c];
        bool l0 = d < f0, l1 = d < f1, l2 = d < f2;
        f2 = l1 ? f1 : (l2 ? d : f2);  m2i = l1 ? m1i : (l2 ? j : m2i);
        f1 = l0 ? f0 : (l1 ? d : f1);  m1i = l0 ? m0i : (l1 ? j : m1i);
        f0 = l0 ? d : f0;              m0i = l0 ? j : m0i;
      }
    float w0 = 1.0f / (f0 + 1e-8f), w1 = 1.0f / (f1 + 1e-8f), w2 = 1.0f / (f2 + 1e-8f);
    float ws = (w0 + w1) + w2;
    sw[0][t] = w0 / ws; sw[1][t] = w1 / ws; sw[2][t] = w2 / ws;
    si[0][t] = m0i; si[1][t] = m1i; si[2][t] = m2i;
  }
  __syncthreads();

  // ---- gather: vectorized float4 rows (row index wave-uniform -> 1KB loads)
  const floatx4* xf4 = (const floatx4*)(x_feats + (size_t)b * NXP * CXC);
  const floatx4* yf4 = (const floatx4*)(y_feats + ((size_t)b * NYTOT + chunk * 128) * CYC);
  half_t* fb = A0 + ((size_t)b * NYTOT + chunk * 128) * DIMC;
  {
    const int q = t & 63;           // float4 index within 256-ch row
    const int ysub = t >> 6;        // 16 y-groups
    for (int y2 = ysub; y2 < 128; y2 += 16) {
      int j0 = si[0][y2], j1 = si[1][y2], j2 = si[2][y2];
      float a0 = sw[0][y2], a1 = sw[1][y2], a2 = sw[2][y2];
      floatx4 v0 = xf4[(size_t)j0 * 64 + q];
      floatx4 v1 = xf4[(size_t)j1 * 64 + q];
      floatx4 v2 = xf4[(size_t)j2 * 64 + q];
      half4 h;
#pragma unroll
      for (int e = 0; e < 4; ++e)
        h[e] = (half_t)fmaf(v2[e], a2, fmaf(v1[e], a1, v0[e] * a0));
      *(half4*)&fb[(size_t)y2 * DIMC + CYC + q * 4] = h;
    }
  }
  {
    const int q2 = t & 31;          // float4 index within 128-ch row
    const int ysub2 = t >> 5;       // 32 y-groups
    for (int y2 = ysub2; y2 < 128; y2 += 32) {
      floatx4 v = yf4[(size_t)y2 * 32 + q2];
      half4 h;
#pragma unroll
      for (int e = 0; e < 4; ++e) h[e] = (half_t)v[e];
      *(half4*)&fb[(size_t)y2 * DIMC + q2 * 4] = h;
    }
  }
}

// ---------------- GEMM 256x128 (round-5 verified; best measured config) --
// 256x128 M*N tile, BK=64, 512 thr (8 waves, 4Mx2N), mfma_f32_16x16x32_f16.
// 1D grid, n-fastest decode + bijective XCD-chunk swizzle.
template<int K, int O, int NTN, bool FUSEA>
__global__ __launch_bounds__(512) void gemm256(
    const half_t* __restrict__ A, const half_t* __restrict__ Wh,
    const float* __restrict__ bias, half_t* __restrict__ C,
    float* __restrict__ sums, const float* __restrict__ ssA) {
  __shared__ __align__(16) short As[16][2][512];  // 32 KB
  __shared__ __align__(16) short Bs[8][2][512];   // 16 KB
  constexpr int NWG = (MTOT / 256) * NTN;         // multiple of 8
  const int lin = (blockIdx.x & 7) * (NWG >> 3) + (blockIdx.x >> 3);
  const int m0 = (lin / NTN) * 256;
  const int n0 = (lin % NTN) * 128;
  const int tid = threadIdx.x;
  const int lane = tid & 63;
  const int wid = tid >> 6;            // 0..7
  const int wm = wid >> 1, wn = wid & 1;
  const int lm = lane & 15;
  const int lk = (lane >> 4) * 8;
  floatx4 acc[4][4] = {};

  for (int k0 = 0; k0 < K; k0 += 64) {
    __syncthreads();
    if constexpr (FUSEA) {
#pragma unroll
      for (int c = 0; c < 2; ++c) {
        int id = wid * 2 + c;          // 0..15 (wave-uniform)
        int sub = id >> 1, ks = id & 1;
        const half_t* src = Wh + (size_t)(n0 + sub * 16 + lm) * K + (k0 + ks * 32 + lk);
        __builtin_amdgcn_global_load_lds(
            (const __attribute__((address_space(1))) void*)src,
            (__attribute__((address_space(3))) void*)&Bs[sub][ks][0], 16, 0, 0);
      }
      const int r = tid & 255;
      const int hh = tid >> 8;
      const half_t* arow = A + (size_t)(m0 + r) * K + k0 + hh * 32;
      half8 in[4];
#pragma unroll
      for (int g = 0; g < 4; ++g) in[g] = *(const half8*)&arow[g * 8];
#pragma unroll
      for (int g = 0; g < 4; ++g) {
        int kc = k0 + hh * 32 + g * 8;
        half8 h;
#pragma unroll
        for (int e = 0; e < 8; ++e) {
          float f = fmaxf((float)in[g][e] * ssA[kc + e] + ssA[K + kc + e], 0.f);
          h[e] = (half_t)f;
        }
        *(half8*)&As[r >> 4][hh][(g * 16 + (r & 15)) * 8] = h;
      }
    } else {
#pragma unroll
      for (int c = 0; c < 6; ++c) {
        int id = wid * 6 + c;          // 0..47
        if (id < 32) {
          int sub = id >> 1, ks = id & 1;
          const half_t* src = A + (size_t)(m0 + sub * 16 + lm) * K + (k0 + ks * 32 + lk);
          __builtin_amdgcn_global_load_lds(
              (const __attribute__((address_space(1))) void*)src,
              (__attribute__((address_space(3))) void*)&As[sub][ks][0], 16, 0, 0);
        } else {
          int id2 = id - 32;
          int sub = id2 >> 1, ks = id2 & 1;
          const half_t* src = Wh + (size_t)(n0 + sub * 16 + lm) * K + (k0 + ks * 32 + lk);
          __builtin_amdgcn_global_load_lds(
              (const __attribute__((address_space(1))) void*)src,
              (__attribute__((address_space(3))) void*)&Bs[sub][ks][0], 16, 0, 0);
        }
      }
    }
    __syncthreads();
#pragma unroll
    for (int ks = 0; ks < 2; ++ks) {
      half8 af[4], bfm[4];
#pragma unroll
      for (int i = 0; i < 4; ++i) af[i] = *(const half8*)&As[wm * 4 + i][ks][lane * 8];
#pragma unroll
      for (int j = 0; j < 4; ++j) bfm[j] = *(const half8*)&Bs[wn * 4 + j][ks][lane * 8];
#pragma unroll
      for (int i = 0; i < 4; ++i)
#pragma unroll
        for (int j = 0; j < 4; ++j)
          acc[i][j] = __builtin_amdgcn_mfma_f32_16x16x32_f16(af[i], bfm[j], acc[i][j], 0, 0, 0);
    }
  }

  // epilogue: C/D layout col=lane&15, row=(lane>>4)*4+rr; fused BN stats
#pragma unroll
  for (int j = 0; j < 4; ++j) {
    int nn = n0 + wn * 64 + j * 16 + lm;
    float bv = bias[nn];
    float psum = 0.f, psq = 0.f;
#pragma unroll
    for (int i = 0; i < 4; ++i) {
      int mr = m0 + wm * 64 + i * 16 + (lane >> 4) * 4;
#pragma unroll
      for (int rr = 0; rr < 4; ++rr) {
        float z = acc[i][j][rr] + bv;
        C[(size_t)(mr + rr) * O + nn] = (half_t)z;
        psum += z; psq += z * z;
      }
    }
    psum += __shfl_xor(psum, 16, 64); psq += __shfl_xor(psq, 16, 64);
    psum += __shfl_xor(psum, 32, 64); psq += __shfl_xor(psq, 32, 64);
    if ((lane >> 4) == 0) {
      atomicAdd(&sums[nn], psum);
      atomicAdd(&sums[O + nn], psq);
    }
  }
}

// ---------------- GEMM 128x128 (verified; gemm3) -------------------------
// TOUT: store z directly in the FINAL [b][c][n] layout (b = m>>14 is
// block-uniform since 16384%128==0; n = m&16383; rr runs along n so the
// 4-value fragment is a contiguous half4 — better coalescing than the
// scalar row-major stores, and kills the separate LDS-transpose pass).
template<int K, int O, bool FUSEA, bool TOUT>
__global__ __launch_bounds__(256) void gemm_f16(
    const half_t* __restrict__ A, const half_t* __restrict__ Wh,
    const float* __restrict__ bias, half_t* __restrict__ C,
    float* __restrict__ sums, const float* __restrict__ ssA) {
  __shared__ __align__(16) short As[8][2][512];   // [m_sub][k_sub][lane*8+e]
  __shared__ __align__(16) short Bs[8][2][512];
  const int m0 = blockIdx.x * 128;
  const int n0 = blockIdx.y * 128;
  const int tid = threadIdx.x;
  const int lane = tid & 63;
  const int wid = tid >> 6;
  const int wm = wid >> 1, wn = wid & 1;
  const int lm = lane & 15;
  const int lk = (lane >> 4) * 8;
  floatx4 acc[4][4] = {};

  for (int k0 = 0; k0 < K; k0 += 64) {
    __syncthreads();
    if constexpr (FUSEA) {
#pragma unroll
      for (int c = 0; c < 4; ++c) {
        int id = wid * 4 + c;          // 0..15
        int sub = id >> 1;
        int ks = id & 1;
        const half_t* src = Wh + (size_t)(n0 + sub * 16 + lm) * K + (k0 + ks * 32 + lk);
        __builtin_amdgcn_global_load_lds(
            (const __attribute__((address_space(1))) void*)src,
            (__attribute__((address_space(3))) void*)&Bs[sub][ks][0], 16, 0, 0);
      }
      const int r = tid & 127;
      const int hh = tid >> 7;
      const half_t* arow = A + (size_t)(m0 + r) * K + k0 + hh * 32;
      half8 in[4];
#pragma unroll
      for (int g = 0; g < 4; ++g) in[g] = *(const half8*)&arow[g * 8];
#pragma unroll
      for (int g = 0; g < 4; ++g) {
        int kc = k0 + hh * 32 + g * 8;
        half8 h;
#pragma unroll
        for (int e = 0; e < 8; ++e) {
          float f = fmaxf((float)in[g][e] * ssA[kc + e] + ssA[K + kc + e], 0.f);
          h[e] = (half_t)f;
        }
        *(half8*)&As[r >> 4][hh][(g * 16 + (r & 15)) * 8] = h;
      }
    } else {
#pragma unroll
      for (int c = 0; c < 8; ++c) {
        int id = wid * 8 + c;          // 0..31 (wave-uniform)
        int sub = (id >> 1) & 7;
        int ks = id & 1;
        const half_t* src = (id < 16)
            ? A  + (size_t)(m0 + sub * 16 + lm) * K + (k0 + ks * 32 + lk)
            : Wh + (size_t)(n0 + sub * 16 + lm) * K + (k0 + ks * 32 + lk);
        __builtin_amdgcn_global_load_lds(
            (const __attribute__((address_space(1))) void*)src,
            (__attribute__((address_space(3))) void*)(id < 16 ? &As[sub][ks][0]
                                                             : &Bs[sub][ks][0]),
            16, 0, 0);
      }
    }
    __syncthreads();
#pragma unroll
    for (int ks = 0; ks < 2; ++ks) {
      half8 af[4], bfm[4];
#pragma unroll
      for (int i = 0; i < 4; ++i) af[i] = *(const half8*)&As[wm * 4 + i][ks][lane * 8];
#pragma unroll
      for (int j = 0; j < 4; ++j) bfm[j] = *(const half8*)&Bs[wn * 4 + j][ks][lane * 8];
#pragma unroll
      for (int i = 0; i < 4; ++i)
#pragma unroll
        for (int j = 0; j < 4; ++j)
          acc[i][j] = __builtin_amdgcn_mfma_f32_16x16x32_f16(af[i], bfm[j], acc[i][j], 0, 0, 0);
    }
  }

  const int bb = m0 >> 14;                 // block-uniform batch (TOUT)
  const int nbase = (m0 & (NYTOT - 1)) + wm * 64 + (lane >> 4) * 4;
#pragma unroll
  for (int j = 0; j < 4; ++j) {
    int nn = n0 + wn * 64 + j * 16 + lm;
    float bv = bias[nn];
    float psum = 0.f, psq = 0.f;
#pragma unroll
    for (int i = 0; i < 4; ++i) {
      half4 hv;
#pragma unroll
      for (int rr = 0; rr < 4; ++rr) {
        float z = acc[i][j][rr] + bv;
        hv[rr] = (half_t)z;
        psum += z; psq += z * z;
      }
      if constexpr (TOUT) {
        *(half4*)&C[((size_t)(bb * O + nn)) * NYTOT + nbase + i * 16] = hv;
      } else {
        int mr = m0 + wm * 64 + i * 16 + (lane >> 4) * 4;
#pragma unroll
        for (int rr = 0; rr < 4; ++rr)
          C[(size_t)(mr + rr) * O + nn] = hv[rr];
      }
    }
    psum += __shfl_xor(psum, 16, 64); psq += __shfl_xor(psq, 16, 64);
    psum += __shfl_xor(psum, 32, 64); psq += __shfl_xor(psq, 32, 64);
    if ((lane >> 4) == 0) {
      atomicAdd(&sums[nn], psum);
      atomicAdd(&sums[O + nn], psq);
    }
  }
}

// ---------------- finalize BN scale/shift ----------
__global__ void finalize_kernel(const float* __restrict__ sums, const float* __restrict__ g,
                                const float* __restrict__ be, float* __restrict__ ss, int O) {
  int c = threadIdx.x;
  if (c < O) {
    const float invN = 1.0f / 65536.0f;
    float mean = sums[c] * invN;
    float var = sums[O + c] * invN - mean * mean;
    float sc = g[c] / sqrtf(var + 1e-5f);
    float sh = be[c] - mean * sc;
    if (!isfinite(sc) || !isfinite(sh)) { sc = 1.0f; sh = 0.0f; }
    ss[c] = sc;
    ss[O + c] = sh;
  }
}

// ---------------- final: elementwise BN3+ReLU fp16->fp32 ----------------
// z3T is already in output layout [b][c][n]; channel = (idx*8 >> 14) & 127.
__global__ __launch_bounds__(256) void bnfin_kernel(
    const half_t* __restrict__ Z, const float* __restrict__ ss,
    float* __restrict__ out) {
  size_t i = (size_t)blockIdx.x * 256 + threadIdx.x;   // HF8 index (1M total)
  int c = (int)((i * 8) >> 14) & 127;
  float sc = ss[c], sh = ss[128 + c];
  HF8 v = ((const HF8*)Z)[i];
  floatx4 o0, o1;
#pragma unroll
  for (int e = 0; e < 4; ++e) {
    o0[e] = fmaxf((float)v.h[e] * sc + sh, 0.f);
    o1[e] = fmaxf((float)v.h[4 + e] * sc + sh, 0.f);
  }
  ((floatx4*)out)[i * 2] = o0;
  ((floatx4*)out)[i * 2 + 1] = o1;
}

extern "C" void kernel_launch(void* const* d_in, const int* in_sizes, int n_in,
                              void* d_out, int out_size, void* d_ws, size_t ws_size,
                              hipStream_t stream) {
  const float* y_points = (const float*)d_in[0];
  const float* y_feats  = (const float*)d_in[1];
  const float* x_points = (const float*)d_in[2];
  const float* x_feats  = (const float*)d_in[3];
  const float* W1 = (const float*)d_in[4];  const float* b1 = (const float*)d_in[5];
  const float* g1 = (const float*)d_in[6];  const float* be1 = (const float*)d_in[7];
  const float* W2 = (const float*)d_in[8];  const float* b2 = (const float*)d_in[9];
  const float* g2 = (const float*)d_in[10]; const float* be2 = (const float*)d_in[11];
  const float* W3 = (const float*)d_in[12]; const float* b3 = (const float*)d_in[13];
  const float* g3 = (const float*)d_in[14]; const float* be3 = (const float*)d_in[15];

  // workspace layout (peak unchanged):
  //   [0, 50.33MB)        : A0 fp16 [M,384]  (later aliased by z2)
  //   [50.33MB, 117.44MB) : z1 fp16 [M,512]  (xq table lives here pre-gemm1,
  //                         later aliased by z3T in [b][c][n] layout)
  //   [117.44MB, ...)     : BN stats
  // d_out (33.5 MB) doubles as scratch for fp16 weights until bnfin.
  char* ws = (char*)d_ws;
  half_t* A0 = (half_t*)ws;                      // 65536*384*2 = 50,331,648
  half_t* z1 = (half_t*)(ws + 50331648);         // 65536*512*2 = 67,108,864
  half_t* z2 = (half_t*)ws;                      // alias A0 (dead after gemm1)
  half_t* z3T = (half_t*)(ws + 50331648);        // alias z1 (dead after gemm2)
  float4* xq = (float4*)(ws + 50331648);         // alias z1 head (dead before gemm1)
  float* st = (float*)(ws + 117440512);
  // st floats: sum1/sq1 @0 (1024), sum2/sq2 @1024 (512), sum3/sq3 @1536 (256),
  //            ss1 @1792 (1024), ss2 @2816 (512), ss3 @3328 (256)
  half_t* W1h = (half_t*)d_out;                  // 512*384  = 196608 halfs
  half_t* W2h = W1h + 196608;                    // 256*512  = 131072 halfs
  half_t* W3h = W1h + 327680;                    // 128*256  =  32768 halfs
  hipMemsetAsync(st, 0, 1792 * sizeof(float), stream);

  prep_kernel<<<416, 256, 0, stream>>>(x_points, xq, W1, W2, W3, W1h);
  interp_kernel<<<512, 1024, 0, stream>>>(y_points, y_feats, x_feats, xq, A0);

  // gemm1: 256x128 tile, 1024 blocks (XCD-swizzled, n-fastest)
  gemm256<384, 512, 4, false><<<1024, 512, 0, stream>>>(A0, W1h, b1, z1, st + 0, nullptr);
  finalize_kernel<<<1, 512, 0, stream>>>(st + 0, g1, be1, st + 1792, 512);

  // gemm2: 256x128 tile, BN1+ReLU fused into A-staging
  gemm256<512, 256, 2, true><<<512, 512, 0, stream>>>(z1, W2h, b2, z2, st + 1024, st + 1792);
  finalize_kernel<<<1, 256, 0, stream>>>(st + 1024, g2, be2, st + 2816, 256);

  // gemm3: 128x128 tile, BN2+ReLU fused into A-staging; output stored
  // directly in final [b][c][n] layout
  gemm_f16<256, 128, true, true><<<dim3(512, 1), 256, 0, stream>>>(z2, W3h, b3, z3T, st + 1536, st + 2816);
  finalize_kernel<<<1, 128, 0, stream>>>(st + 1536, g3, be3, st + 3328, 128);

  // final: elementwise BN3+ReLU fp16->fp32 (no transpose needed)
  bnfin_kernel<<<4096, 256, 0, stream>>>(z3T, st + 3328, (float*)d_out);
}

// Round 11
// 447.236 us; speedup vs baseline: 1.0734x; 1.0306x over previous
//
#include <hip/hip_runtime.h>

#define NYTOT 16384
#define NXP 4096
#define MTOT 65536   // B * NY
#define CYC 128
#define CXC 256
#define DIMC 384

typedef __attribute__((ext_vector_type(8))) _Float16 half8;
typedef __attribute__((ext_vector_type(4))) _Float16 half4;
typedef __attribute__((ext_vector_type(4))) float floatx4;
typedef __attribute__((ext_vector_type(2))) float floatx2;

using half_t = _Float16;

struct alignas(16) HF8 { half_t h[8]; };

__device__ __forceinline__ float fmed3(float a, float b, float c) {
  return __builtin_amdgcn_fmed3f(a, b, c);
}

// ---------------- K0: merged prep — xq table + fp32->fp16 weights --------
__global__ __launch_bounds__(256) void prep_kernel(
    const float* __restrict__ x_points, float4* __restrict__ xq,
    const float* __restrict__ W1, const float* __restrict__ W2,
    const float* __restrict__ W3, half_t* __restrict__ wout) {
#pragma clang fp contract(off)
  const int bid = blockIdx.x;
  if (bid < 64) {
    int j = bid * 256 + threadIdx.x;          // 0..16383
    int b = j >> 12, jj = j & 4095;
    const float* p = x_points + (size_t)b * NXP * 3 + 3 * jj;
    float x0 = p[0], x1 = p[1], x2 = p[2];
    float sx = (x0 * x0 + x1 * x1) + x2 * x2; // ref order
    float4 v; v.x = x0; v.y = x1; v.z = x2; v.w = sx;
    xq[j] = v;
  } else {
    int i = (bid - 64) * 256 + threadIdx.x;   // float4 index, 0..90111
    const float* src; half_t* dst; int j;
    if (i < 49152)      { src = W1; dst = wout;          j = i; }
    else if (i < 81920) { src = W2; dst = wout + 196608; j = i - 49152; }
    else                { src = W3; dst = wout + 327680; j = i - 81920; }
    floatx4 v = ((const floatx4*)src)[j];
    half4 h;
#pragma unroll
    for (int e = 0; e < 4; ++e) h[e] = (half_t)v[e];
    ((half4*)dst)[j] = h;
  }
}

// ---------------- K1: 3-NN interpolation (round-5/8/10 verified) ---------
__global__ __launch_bounds__(1024, 8) void interp_kernel(
    const float* __restrict__ y_points, const float* __restrict__ y_feats,
    const float* __restrict__ x_feats, const float4* __restrict__ xq,
    half_t* __restrict__ A0) {
#pragma clang fp contract(off)
  __shared__ float pd[16][128][3];        // 24 KB partial dists
  __shared__ int   pi[16][128][3];        // 24 KB partial idx
  __shared__ float t2s[128];
  __shared__ float sw[3][128];
  __shared__ int   si[3][128];
  const int b = blockIdx.x >> 7;
  const int chunk = blockIdx.x & 127;
  const int t = threadIdx.x;
  const int lane = t & 63;
  const int seg = t >> 6;                 // wave id == segment, 0..15
  const int yloc = lane << 1;             // my 2 y's: yloc, yloc+1

  const float* yp = y_points + ((size_t)b * NYTOT + chunk * 128 + yloc) * 3;
  floatx2 Y0 = {yp[0], yp[3]};
  floatx2 Y1 = {yp[1], yp[4]};
  floatx2 Y2 = {yp[2], yp[5]};
  floatx2 SY = (Y0 * Y0 + Y1 * Y1) + Y2 * Y2;       // ref order per element

  const float4* xqs = xq + (size_t)b * NXP;
  const int jb = __builtin_amdgcn_readfirstlane(seg * 256);

  // ---- phase 1: value-only top-3 per (seg, y) via med3/min ----
  floatx2 D0 = {1e30f, 1e30f}, D1 = D0, D2 = D0;
#pragma unroll 8
  for (int jj = 0; jj < 256; ++jj) {
    float4 p = xqs[jb + jj];                        // wave-uniform load
    floatx2 inner = (Y0 * p.x + Y1 * p.y) + Y2 * p.z;
    floatx2 d = (SY + p.w) - 2.0f * inner;
    D2.x = fmed3(d.x, D1.x, D2.x);  D2.y = fmed3(d.y, D1.y, D2.y);
    D1.x = fmed3(d.x, D0.x, D1.x);  D1.y = fmed3(d.y, D0.y, D1.y);
    D0.x = fminf(d.x, D0.x);        D0.y = fminf(d.y, D0.y);
  }
  pd[seg][yloc][0] = D0.x; pd[seg][yloc][1] = D1.x; pd[seg][yloc][2] = D2.x;
  pd[seg][yloc + 1][0] = D0.y; pd[seg][yloc + 1][1] = D1.y; pd[seg][yloc + 1][2] = D2.y;
  __syncthreads();

  // global 3rd-smallest per y
  if (t < 128) {
    float m0 = 1e30f, m1 = 1e30f, m2 = 1e30f;
#pragma unroll
    for (int s = 0; s < 16; ++s)
#pragma unroll
      for (int c = 0; c < 3; ++c) {
        float v = pd[s][t][c];
        m2 = fmed3(v, m1, m2);
        m1 = fmed3(v, m0, m1);
        m0 = fminf(v, m0);
      }
    t2s[t] = m2;
  }
  __syncthreads();

  // ---- phase 2: gated stable index recovery ----
  const float t2a = t2s[yloc], t2b = t2s[yloc + 1];
  const float tmax = fmaxf(t2a, t2b);
  float e0a = 1e30f, e1a = 1e30f, e2a = 1e30f; int k0a = 0, k1a = 0, k2a = 0;
  float e0b = 1e30f, e1b = 1e30f, e2b = 1e30f; int k0b = 0, k1b = 0, k2b = 0;
#pragma unroll 4
  for (int jj = 0; jj < 256; ++jj) {
    float4 p = xqs[jb + jj];
    floatx2 inner = (Y0 * p.x + Y1 * p.y) + Y2 * p.z;
    floatx2 d = (SY + p.w) - 2.0f * inner;
    if (fminf(d.x, d.y) <= tmax) {                  // rare
      int j = jb + jj;
      {
        float dv = d.x;
        bool l0 = dv < e0a, l1 = dv < e1a, l2 = dv < e2a;
        e2a = l1 ? e1a : (l2 ? dv : e2a);  k2a = l1 ? k1a : (l2 ? j : k2a);
        e1a = l0 ? e0a : (l1 ? dv : e1a);  k1a = l0 ? k0a : (l1 ? j : k1a);
        e0a = l0 ? dv : e0a;               k0a = l0 ? j : k0a;
      }
      {
        float dv = d.y;
        bool l0 = dv < e0b, l1 = dv < e1b, l2 = dv < e2b;
        e2b = l1 ? e1b : (l2 ? dv : e2b);  k2b = l1 ? k1b : (l2 ? j : k2b);
        e1b = l0 ? e0b : (l1 ? dv : e1b);  k1b = l0 ? k0b : (l1 ? j : k1b);
        e0b = l0 ? dv : e0b;               k0b = l0 ? j : k0b;
      }
    }
  }
  pd[seg][yloc][0] = e0a; pd[seg][yloc][1] = e1a; pd[seg][yloc][2] = e2a;
  pi[seg][yloc][0] = k0a; pi[seg][yloc][1] = k1a; pi[seg][yloc][2] = k2a;
  pd[seg][yloc + 1][0] = e0b; pd[seg][yloc + 1][1] = e1b; pd[seg][yloc + 1][2] = e2b;
  pi[seg][yloc + 1][0] = k0b; pi[seg][yloc + 1][1] = k1b; pi[seg][yloc + 1][2] = k2b;
  __syncthreads();

  // 48-way stable merge (seg-ascending) + weights
  if (t < 128) {
    float f0 = 1e30f, f1 = 1e30f, f2 = 1e30f;
    int m0i = 0, m1i = 0, m2i = 0;
#pragma unroll
    for (int s = 0; s < 16; ++s)
#pragma unroll
      for (int c = 0; c < 3; ++c) {
        float d = pd[s][t][c]; int j = pi[s][t][c];
        bool l0 = d < f0, l1 = d < f1, l2 = d < f2;
        f2 = l1 ? f1 : (l2 ? d : f2);  m2i = l1 ? m1i : (l2 ? j : m2i);
        f1 = l0 ? f0 : (l1 ? d : f1);  m1i = l0 ? m0i : (l1 ? j : m1i);
        f0 = l0 ? d : f0;              m0i = l0 ? j : m0i;
      }
    float w0 = 1.0f / (f0 + 1e-8f), w1 = 1.0f / (f1 + 1e-8f), w2 = 1.0f / (f2 + 1e-8f);
    float ws = (w0 + w1) + w2;
    sw[0][t] = w0 / ws; sw[1][t] = w1 / ws; sw[2][t] = w2 / ws;
    si[0][t] = m0i; si[1][t] = m1i; si[2][t] = m2i;
  }
  __syncthreads();

  // ---- gather ----
  const floatx4* xf4 = (const floatx4*)(x_feats + (size_t)b * NXP * CXC);
  const floatx4* yf4 = (const floatx4*)(y_feats + ((size_t)b * NYTOT + chunk * 128) * CYC);
  half_t* fb = A0 + ((size_t)b * NYTOT + chunk * 128) * DIMC;
  {
    const int q = t & 63;
    const int ysub = t >> 6;
    for (int y2 = ysub; y2 < 128; y2 += 16) {
      int j0 = si[0][y2], j1 = si[1][y2], j2 = si[2][y2];
      float a0 = sw[0][y2], a1 = sw[1][y2], a2 = sw[2][y2];
      floatx4 v0 = xf4[(size_t)j0 * 64 + q];
      floatx4 v1 = xf4[(size_t)j1 * 64 + q];
      floatx4 v2 = xf4[(size_t)j2 * 64 + q];
      half4 h;
#pragma unroll
      for (int e = 0; e < 4; ++e)
        h[e] = (half_t)fmaf(v2[e], a2, fmaf(v1[e], a1, v0[e] * a0));
      *(half4*)&fb[(size_t)y2 * DIMC + CYC + q * 4] = h;
    }
  }
  {
    const int q2 = t & 31;
    const int ysub2 = t >> 5;
    for (int y2 = ysub2; y2 < 128; y2 += 32) {
      floatx4 v = yf4[(size_t)y2 * 32 + q2];
      half4 h;
#pragma unroll
      for (int e = 0; e < 4; ++e) h[e] = (half_t)v[e];
      *(half4*)&fb[(size_t)y2 * DIMC + q2 * 4] = h;
    }
  }
}

// ---------------- GEMM 256x128, 2-phase pipelined staging ---------------
// A reg-staged (identical fragment layout to the verified FUSEA path; BN
// transform optional). Per K-step t: [barrier A] ds_write A(t) from regs
// (loaded LAST iteration -> latency already hidden); [barrier B]; issue
// B(t+1) gload_lds into dbuf + issue A(t+1) reg loads; ds_read + MFMA(t)
// covers their latency; they drain at next iteration's barrier A.
// BN stats: per-block LDS pre-reduce over the 4 wm-waves -> 256 atomics
// per block (was 1024).
template<int K, int O, int NTN, bool BN>
__global__ __launch_bounds__(512) void gemm256p(
    const half_t* __restrict__ A, const half_t* __restrict__ Wh,
    const float* __restrict__ bias, half_t* __restrict__ C,
    float* __restrict__ sums, const float* __restrict__ ssA) {
  __shared__ __align__(16) short As[16][2][512];     // 32 KB (single buf)
  __shared__ __align__(16) short Bs[2][8][2][512];   // 32 KB (double buf)
  __shared__ float stats[4][2][128];                 // 4 KB
  constexpr int NWG = (MTOT / 256) * NTN;            // multiple of 8
  constexpr int NT = K / 64;
  const int lin = (blockIdx.x & 7) * (NWG >> 3) + (blockIdx.x >> 3);
  const int m0 = (lin / NTN) * 256;
  const int n0 = (lin % NTN) * 128;
  const int tid = threadIdx.x;
  const int lane = tid & 63;
  const int wid = tid >> 6;            // 0..7
  const int wm = wid >> 1, wn = wid & 1;
  const int lm = lane & 15;
  const int lk = (lane >> 4) * 8;
  const int r = tid & 255;             // A-stage row
  const int hh = tid >> 8;             // A-stage k-half
  floatx4 acc[4][4] = {};
  half8 in[4];

  // prologue: B(0) -> Bs[0]; A(0) -> regs
#pragma unroll
  for (int c = 0; c < 2; ++c) {
    int id = wid * 2 + c;              // 0..15 (wave-uniform)
    int sub = id >> 1, ks = id & 1;
    const half_t* src = Wh + (size_t)(n0 + sub * 16 + lm) * K + (ks * 32 + lk);
    __builtin_amdgcn_global_load_lds(
        (const __attribute__((address_space(1))) void*)src,
        (__attribute__((address_space(3))) void*)&Bs[0][sub][ks][0], 16, 0, 0);
  }
  {
    const half_t* arow = A + (size_t)(m0 + r) * K + hh * 32;
#pragma unroll
    for (int g = 0; g < 4; ++g) in[g] = *(const half8*)&arow[g * 8];
  }
  int cur = 0;

  for (int t = 0; t < NT; ++t) {
    const int k0 = t * 64;
    __syncthreads();                   // (A) As free; prev-iter vmem drained
    // A-write tile t (regs already landed)
#pragma unroll
    for (int g = 0; g < 4; ++g) {
      half8 h;
      if constexpr (BN) {
        int kc = k0 + hh * 32 + g * 8;
#pragma unroll
        for (int e = 0; e < 8; ++e) {
          float f = fmaxf((float)in[g][e] * ssA[kc + e] + ssA[K + kc + e], 0.f);
          h[e] = (half_t)f;
        }
      } else {
        h = in[g];
      }
      *(half8*)&As[r >> 4][hh][(g * 16 + (r & 15)) * 8] = h;
    }
    __syncthreads();                   // (B) As + Bs[cur] ready
    if (t + 1 < NT) {
      const int k1 = k0 + 64;
#pragma unroll
      for (int c = 0; c < 2; ++c) {    // B(t+1) -> Bs[cur^1]
        int id = wid * 2 + c;
        int sub = id >> 1, ks = id & 1;
        const half_t* src = Wh + (size_t)(n0 + sub * 16 + lm) * K + (k1 + ks * 32 + lk);
        __builtin_amdgcn_global_load_lds(
            (const __attribute__((address_space(1))) void*)src,
            (__attribute__((address_space(3))) void*)&Bs[cur ^ 1][sub][ks][0], 16, 0, 0);
      }
      const half_t* arow = A + (size_t)(m0 + r) * K + k1 + hh * 32;
#pragma unroll
      for (int g = 0; g < 4; ++g) in[g] = *(const half8*)&arow[g * 8];
    }
    // compute tile t (latency of the new loads hides under this)
#pragma unroll
    for (int ks = 0; ks < 2; ++ks) {
      half8 af[4], bfm[4];
#pragma unroll
      for (int i = 0; i < 4; ++i) af[i] = *(const half8*)&As[wm * 4 + i][ks][lane * 8];
#pragma unroll
      for (int j = 0; j < 4; ++j) bfm[j] = *(const half8*)&Bs[cur][wn * 4 + j][ks][lane * 8];
#pragma unroll
      for (int i = 0; i < 4; ++i)
#pragma unroll
        for (int j = 0; j < 4; ++j)
          acc[i][j] = __builtin_amdgcn_mfma_f32_16x16x32_f16(af[i], bfm[j], acc[i][j], 0, 0, 0);
    }
    cur ^= 1;
  }

  // epilogue: C/D layout col=lane&15, row=(lane>>4)*4+rr
  float ps[4], pq[4];
#pragma unroll
  for (int j = 0; j < 4; ++j) {
    int nn = n0 + wn * 64 + j * 16 + lm;
    float bv = bias[nn];
    float psum = 0.f, psq = 0.f;
#pragma unroll
    for (int i = 0; i < 4; ++i) {
      int mr = m0 + wm * 64 + i * 16 + (lane >> 4) * 4;
#pragma unroll
      for (int rr = 0; rr < 4; ++rr) {
        float z = acc[i][j][rr] + bv;
        C[(size_t)(mr + rr) * O + nn] = (half_t)z;
        psum += z; psq += z * z;
      }
    }
    psum += __shfl_xor(psum, 16, 64); psq += __shfl_xor(psq, 16, 64);
    psum += __shfl_xor(psum, 32, 64); psq += __shfl_xor(psq, 32, 64);
    ps[j] = psum; pq[j] = psq;
  }
  __syncthreads();                     // all MFMA/LDS reads done
  if ((lane >> 4) == 0) {
#pragma unroll
    for (int j = 0; j < 4; ++j) {
      int ch = wn * 64 + j * 16 + lm;  // 0..127, disjoint per (wn,j)
      stats[wm][0][ch] = ps[j];
      stats[wm][1][ch] = pq[j];
    }
  }
  __syncthreads();
  if (tid < 256) {
    int s = tid >> 7, ch = tid & 127;
    float v = ((stats[0][s][ch] + stats[1][s][ch]) + stats[2][s][ch]) + stats[3][s][ch];
    atomicAdd(&sums[(s ? O : 0) + n0 + ch], v);
  }
}

// ---------------- GEMM 128x128, 2-phase pipelined (gemm3) ---------------
// Same scheme, 4 waves. TOUT: store z directly in final [b][c][n] layout.
template<int K, int O, bool BN, bool TOUT>
__global__ __launch_bounds__(256) void gemm128p(
    const half_t* __restrict__ A, const half_t* __restrict__ Wh,
    const float* __restrict__ bias, half_t* __restrict__ C,
    float* __restrict__ sums, const float* __restrict__ ssA) {
  __shared__ __align__(16) short As[8][2][512];      // 16 KB
  __shared__ __align__(16) short Bs[2][8][2][512];   // 32 KB
  __shared__ float stats[2][2][128];                 // 2 KB
  constexpr int NT = K / 64;
  const int m0 = blockIdx.x * 128;
  const int n0 = blockIdx.y * 128;
  const int tid = threadIdx.x;
  const int lane = tid & 63;
  const int wid = tid >> 6;
  const int wm = wid >> 1, wn = wid & 1;
  const int lm = lane & 15;
  const int lk = (lane >> 4) * 8;
  const int r = tid & 127;
  const int hh = tid >> 7;
  floatx4 acc[4][4] = {};
  half8 in[4];

#pragma unroll
  for (int c = 0; c < 4; ++c) {
    int id = wid * 4 + c;              // 0..15
    int sub = id >> 1, ks = id & 1;
    const half_t* src = Wh + (size_t)(n0 + sub * 16 + lm) * K + (ks * 32 + lk);
    __builtin_amdgcn_global_load_lds(
        (const __attribute__((address_space(1))) void*)src,
        (__attribute__((address_space(3))) void*)&Bs[0][sub][ks][0], 16, 0, 0);
  }
  {
    const half_t* arow = A + (size_t)(m0 + r) * K + hh * 32;
#pragma unroll
    for (int g = 0; g < 4; ++g) in[g] = *(const half8*)&arow[g * 8];
  }
  int cur = 0;

  for (int t = 0; t < NT; ++t) {
    const int k0 = t * 64;
    __syncthreads();                   // (A)
#pragma unroll
    for (int g = 0; g < 4; ++g) {
      half8 h;
      if constexpr (BN) {
        int kc = k0 + hh * 32 + g * 8;
#pragma unroll
        for (int e = 0; e < 8; ++e) {
          float f = fmaxf((float)in[g][e] * ssA[kc + e] + ssA[K + kc + e], 0.f);
          h[e] = (half_t)f;
        }
      } else {
        h = in[g];
      }
      *(half8*)&As[r >> 4][hh][(g * 16 + (r & 15)) * 8] = h;
    }
    __syncthreads();                   // (B)
    if (t + 1 < NT) {
      const int k1 = k0 + 64;
#pragma unroll
      for (int c = 0; c < 4; ++c) {
        int id = wid * 4 + c;
        int sub = id >> 1, ks = id & 1;
        const half_t* src = Wh + (size_t)(n0 + sub * 16 + lm) * K + (k1 + ks * 32 + lk);
        __builtin_amdgcn_global_load_lds(
            (const __attribute__((address_space(1))) void*)src,
            (__attribute__((address_space(3))) void*)&Bs[cur ^ 1][sub][ks][0], 16, 0, 0);
      }
      const half_t* arow = A + (size_t)(m0 + r) * K + k1 + hh * 32;
#pragma unroll
      for (int g = 0; g < 4; ++g) in[g] = *(const half8*)&arow[g * 8];
    }
#pragma unroll
    for (int ks = 0; ks < 2; ++ks) {
      half8 af[4], bfm[4];
#pragma unroll
      for (int i = 0; i < 4; ++i) af[i] = *(const half8*)&As[wm * 4 + i][ks][lane * 8];
#pragma unroll
      for (int j = 0; j < 4; ++j) bfm[j] = *(const half8*)&Bs[cur][wn * 4 + j][ks][lane * 8];
#pragma unroll
      for (int i = 0; i < 4; ++i)
#pragma unroll
        for (int j = 0; j < 4; ++j)
          acc[i][j] = __builtin_amdgcn_mfma_f32_16x16x32_f16(af[i], bfm[j], acc[i][j], 0, 0, 0);
    }
    cur ^= 1;
  }

  const int bb = m0 >> 14;             // block-uniform batch (TOUT)
  const int nbase = (m0 & (NYTOT - 1)) + wm * 64 + (lane >> 4) * 4;
  float ps[4], pq[4];
#pragma unroll
  for (int j = 0; j < 4; ++j) {
    int nn = n0 + wn * 64 + j * 16 + lm;
    float bv = bias[nn];
    float psum = 0.f, psq = 0.f;
#pragma unroll
    for (int i = 0; i < 4; ++i) {
      half4 hv;
#pragma unroll
      for (int rr = 0; rr < 4; ++rr) {
        float z = acc[i][j][rr] + bv;
        hv[rr] = (half_t)z;
        psum += z; psq += z * z;
      }
      if constexpr (TOUT) {
        *(half4*)&C[((size_t)(bb * O + nn)) * NYTOT + nbase + i * 16] = hv;
      } else {
        int mr = m0 + wm * 64 + i * 16 + (lane >> 4) * 4;
#pragma unroll
        for (int rr = 0; rr < 4; ++rr)
          C[(size_t)(mr + rr) * O + nn] = hv[rr];
      }
    }
    psum += __shfl_xor(psum, 16, 64); psq += __shfl_xor(psq, 16, 64);
    psum += __shfl_xor(psum, 32, 64); psq += __shfl_xor(psq, 32, 64);
    ps[j] = psum; pq[j] = psq;
  }
  __syncthreads();
  if ((lane >> 4) == 0) {
#pragma unroll
    for (int j = 0; j < 4; ++j) {
      int ch = wn * 64 + j * 16 + lm;
      stats[wm][0][ch] = ps[j];
      stats[wm][1][ch] = pq[j];
    }
  }
  __syncthreads();
  if (tid < 256) {
    int s = tid >> 7, ch = tid & 127;
    float v = stats[0][s][ch] + stats[1][s][ch];
    atomicAdd(&sums[(s ? O : 0) + n0 + ch], v);
  }
}

// ---------------- finalize BN scale/shift ----------
__global__ void finalize_kernel(const float* __restrict__ sums, const float* __restrict__ g,
                                const float* __restrict__ be, float* __restrict__ ss, int O) {
  int c = threadIdx.x;
  if (c < O) {
    const float invN = 1.0f / 65536.0f;
    float mean = sums[c] * invN;
    float var = sums[O + c] * invN - mean * mean;
    float sc = g[c] / sqrtf(var + 1e-5f);
    float sh = be[c] - mean * sc;
    if (!isfinite(sc) || !isfinite(sh)) { sc = 1.0f; sh = 0.0f; }
    ss[c] = sc;
    ss[O + c] = sh;
  }
}

// ---------------- final: elementwise BN3+ReLU fp16->fp32 ----------------
__global__ __launch_bounds__(256) void bnfin_kernel(
    const half_t* __restrict__ Z, const float* __restrict__ ss,
    float* __restrict__ out) {
  size_t i = (size_t)blockIdx.x * 256 + threadIdx.x;   // HF8 index
  int c = (int)((i * 8) >> 14) & 127;
  float sc = ss[c], sh = ss[128 + c];
  HF8 v = ((const HF8*)Z)[i];
  floatx4 o0, o1;
#pragma unroll
  for (int e = 0; e < 4; ++e) {
    o0[e] = fmaxf((float)v.h[e] * sc + sh, 0.f);
    o1[e] = fmaxf((float)v.h[4 + e] * sc + sh, 0.f);
  }
  ((floatx4*)out)[i * 2] = o0;
  ((floatx4*)out)[i * 2 + 1] = o1;
}

extern "C" void kernel_launch(void* const* d_in, const int* in_sizes, int n_in,
                              void* d_out, int out_size, void* d_ws, size_t ws_size,
                              hipStream_t stream) {
  const float* y_points = (const float*)d_in[0];
  const float* y_feats  = (const float*)d_in[1];
  const float* x_points = (const float*)d_in[2];
  const float* x_feats  = (const float*)d_in[3];
  const float* W1 = (const float*)d_in[4];  const float* b1 = (const float*)d_in[5];
  const float* g1 = (const float*)d_in[6];  const float* be1 = (const float*)d_in[7];
  const float* W2 = (const float*)d_in[8];  const float* b2 = (const float*)d_in[9];
  const float* g2 = (const float*)d_in[10]; const float* be2 = (const float*)d_in[11];
  const float* W3 = (const float*)d_in[12]; const float* b3 = (const float*)d_in[13];
  const float* g3 = (const float*)d_in[14]; const float* be3 = (const float*)d_in[15];

  // workspace layout (peak unchanged):
  //   [0, 50.33MB)        : A0 fp16 [M,384]  (later aliased by z2)
  //   [50.33MB, 117.44MB) : z1 fp16 [M,512]  (xq pre-gemm1; z3T after gemm2)
  //   [117.44MB, ...)     : BN stats
  // d_out (33.5 MB) doubles as scratch for fp16 weights until bnfin.
  char* ws = (char*)d_ws;
  half_t* A0 = (half_t*)ws;                      // 65536*384*2 = 50,331,648
  half_t* z1 = (half_t*)(ws + 50331648);         // 65536*512*2 = 67,108,864
  half_t* z2 = (half_t*)ws;                      // alias A0 (dead after gemm1)
  half_t* z3T = (half_t*)(ws + 50331648);        // alias z1 (dead after gemm2)
  float4* xq = (float4*)(ws + 50331648);         // alias z1 head (dead pre-gemm1)
  float* st = (float*)(ws + 117440512);
  // st floats: sum1/sq1 @0 (1024), sum2/sq2 @1024 (512), sum3/sq3 @1536 (256),
  //            ss1 @1792 (1024), ss2 @2816 (512), ss3 @3328 (256)
  half_t* W1h = (half_t*)d_out;                  // 512*384  = 196608 halfs
  half_t* W2h = W1h + 196608;                    // 256*512  = 131072 halfs
  half_t* W3h = W1h + 327680;                    // 128*256  =  32768 halfs
  hipMemsetAsync(st, 0, 1792 * sizeof(float), stream);

  prep_kernel<<<416, 256, 0, stream>>>(x_points, xq, W1, W2, W3, W1h);
  interp_kernel<<<512, 1024, 0, stream>>>(y_points, y_feats, x_feats, xq, A0);

  // gemm1: 256x128 tile, 1024 blocks (XCD-swizzled, n-fastest), pipelined
  gemm256p<384, 512, 4, false><<<1024, 512, 0, stream>>>(A0, W1h, b1, z1, st + 0, nullptr);
  finalize_kernel<<<1, 512, 0, stream>>>(st + 0, g1, be1, st + 1792, 512);

  // gemm2: 256x128 tile, BN1+ReLU fused into A-staging, pipelined
  gemm256p<512, 256, 2, true><<<512, 512, 0, stream>>>(z1, W2h, b2, z2, st + 1024, st + 1792);
  finalize_kernel<<<1, 256, 0, stream>>>(st + 1024, g2, be2, st + 2816, 256);

  // gemm3: 128x128 tile, BN2+ReLU fused, pipelined, TOUT layout
  gemm128p<256, 128, true, true><<<dim3(512, 1), 256, 0, stream>>>(z2, W3h, b3, z3T, st + 1536, st + 2816);
  finalize_kernel<<<1, 128, 0, stream>>>(st + 1536, g3, be3, st + 3328, 128);

  // final: elementwise BN3+ReLU fp16->fp32 (no transpose needed)
  bnfin_kernel<<<4096, 256, 0, stream>>>(z3T, st + 3328, (float*)d_out);
}

// Round 13
// 441.685 us; speedup vs baseline: 1.0869x; 1.0126x over previous
//
#include <hip/hip_runtime.h>

#define NYTOT 16384
#define NXP 4096
#define MTOT 65536   // B * NY
#define CYC 128
#define CXC 256
#define DIMC 384

typedef __attribute__((ext_vector_type(8))) _Float16 half8;
typedef __attribute__((ext_vector_type(4))) _Float16 half4;
typedef __attribute__((ext_vector_type(4))) float floatx4;
typedef __attribute__((ext_vector_type(2))) float floatx2;

using half_t = _Float16;

struct alignas(16) HF8 { half_t h[8]; };

__device__ __forceinline__ float fmed3(float a, float b, float c) {
  return __builtin_amdgcn_fmed3f(a, b, c);
}

// ---------------- K0: merged prep — xq table + fp16 weights + st zero ----
// blocks 0..63: xq. blocks 64..415: W1/W2/W3 fp32->fp16. block 416: zero
// the BN-stat sums (replaces hipMemsetAsync; in-bounds region st[0..1791]).
__global__ __launch_bounds__(256) void prep_kernel(
    const float* __restrict__ x_points, float4* __restrict__ xq,
    const float* __restrict__ W1, const float* __restrict__ W2,
    const float* __restrict__ W3, half_t* __restrict__ wout,
    float* __restrict__ st) {
#pragma clang fp contract(off)
  const int bid = blockIdx.x;
  if (bid == 416) {
    int t = threadIdx.x;
    for (int k = t; k < 1792; k += 256) st[k] = 0.f;
    return;
  }
  if (bid < 64) {
    int j = bid * 256 + threadIdx.x;          // 0..16383
    int b = j >> 12, jj = j & 4095;
    const float* p = x_points + (size_t)b * NXP * 3 + 3 * jj;
    float x0 = p[0], x1 = p[1], x2 = p[2];
    float sx = (x0 * x0 + x1 * x1) + x2 * x2; // ref order
    float4 v; v.x = x0; v.y = x1; v.z = x2; v.w = sx;
    xq[j] = v;
  } else {
    int i = (bid - 64) * 256 + threadIdx.x;   // float4 index, 0..90111
    const float* src; half_t* dst; int j;
    if (i < 49152)      { src = W1; dst = wout;          j = i; }
    else if (i < 81920) { src = W2; dst = wout + 196608; j = i - 49152; }
    else                { src = W3; dst = wout + 327680; j = i - 81920; }
    floatx4 v = ((const floatx4*)src)[j];
    half4 h;
#pragma unroll
    for (int e = 0; e < 4; ++e) h[e] = (half_t)v[e];
    ((half4*)dst)[j] = h;
  }
}

// ---------------- K1: 3-NN interpolation (round-5/8/10 verified) ---------
// Only change vs r11: phase-1 unroll 8 -> 16 (A/B probe: is phase 1
// scalar-load-latency-bound?).
__global__ __launch_bounds__(1024, 8) void interp_kernel(
    const float* __restrict__ y_points, const float* __restrict__ y_feats,
    const float* __restrict__ x_feats, const float4* __restrict__ xq,
    half_t* __restrict__ A0) {
#pragma clang fp contract(off)
  __shared__ float pd[16][128][3];        // 24 KB partial dists
  __shared__ int   pi[16][128][3];        // 24 KB partial idx
  __shared__ float t2s[128];
  __shared__ float sw[3][128];
  __shared__ int   si[3][128];
  const int b = blockIdx.x >> 7;
  const int chunk = blockIdx.x & 127;
  const int t = threadIdx.x;
  const int lane = t & 63;
  const int seg = t >> 6;                 // wave id == segment, 0..15
  const int yloc = lane << 1;             // my 2 y's: yloc, yloc+1

  const float* yp = y_points + ((size_t)b * NYTOT + chunk * 128 + yloc) * 3;
  floatx2 Y0 = {yp[0], yp[3]};
  floatx2 Y1 = {yp[1], yp[4]};
  floatx2 Y2 = {yp[2], yp[5]};
  floatx2 SY = (Y0 * Y0 + Y1 * Y1) + Y2 * Y2;       // ref order per element

  const float4* xqs = xq + (size_t)b * NXP;
  const int jb = __builtin_amdgcn_readfirstlane(seg * 256);

  // ---- phase 1: value-only top-3 per (seg, y) via med3/min ----
  floatx2 D0 = {1e30f, 1e30f}, D1 = D0, D2 = D0;
#pragma unroll 16
  for (int jj = 0; jj < 256; ++jj) {
    float4 p = xqs[jb + jj];                        // wave-uniform load
    floatx2 inner = (Y0 * p.x + Y1 * p.y) + Y2 * p.z;
    floatx2 d = (SY + p.w) - 2.0f * inner;
    D2.x = fmed3(d.x, D1.x, D2.x);  D2.y = fmed3(d.y, D1.y, D2.y);
    D1.x = fmed3(d.x, D0.x, D1.x);  D1.y = fmed3(d.y, D0.y, D1.y);
    D0.x = fminf(d.x, D0.x);        D0.y = fminf(d.y, D0.y);
  }
  pd[seg][yloc][0] = D0.x; pd[seg][yloc][1] = D1.x; pd[seg][yloc][2] = D2.x;
  pd[seg][yloc + 1][0] = D0.y; pd[seg][yloc + 1][1] = D1.y; pd[seg][yloc + 1][2] = D2.y;
  __syncthreads();

  // global 3rd-smallest per y
  if (t < 128) {
    float m0 = 1e30f, m1 = 1e30f, m2 = 1e30f;
#pragma unroll
    for (int s = 0; s < 16; ++s)
#pragma unroll
      for (int c = 0; c < 3; ++c) {
        float v = pd[s][t][c];
        m2 = fmed3(v, m1, m2);
        m1 = fmed3(v, m0, m1);
        m0 = fminf(v, m0);
      }
    t2s[t] = m2;
  }
  __syncthreads();

  // ---- phase 2: gated stable index recovery ----
  const float t2a = t2s[yloc], t2b = t2s[yloc + 1];
  const float tmax = fmaxf(t2a, t2b);
  float e0a = 1e30f, e1a = 1e30f, e2a = 1e30f; int k0a = 0, k1a = 0, k2a = 0;
  float e0b = 1e30f, e1b = 1e30f, e2b = 1e30f; int k0b = 0, k1b = 0, k2b = 0;
#pragma unroll 4
  for (int jj = 0; jj < 256; ++jj) {
    float4 p = xqs[jb + jj];
    floatx2 inner = (Y0 * p.x + Y1 * p.y) + Y2 * p.z;
    floatx2 d = (SY + p.w) - 2.0f * inner;
    if (fminf(d.x, d.y) <= tmax) {                  // rare
      int j = jb + jj;
      {
        float dv = d.x;
        bool l0 = dv < e0a, l1 = dv < e1a, l2 = dv < e2a;
        e2a = l1 ? e1a : (l2 ? dv : e2a);  k2a = l1 ? k1a : (l2 ? j : k2a);
        e1a = l0 ? e0a : (l1 ? dv : e1a);  k1a = l0 ? k0a : (l1 ? j : k1a);
        e0a = l0 ? dv : e0a;               k0a = l0 ? j : k0a;
      }
      {
        float dv = d.y;
        bool l0 = dv < e0b, l1 = dv < e1b, l2 = dv < e2b;
        e2b = l1 ? e1b : (l2 ? dv : e2b);  k2b = l1 ? k1b : (l2 ? j : k2b);
        e1b = l0 ? e0b : (l1 ? dv : e1b);  k1b = l0 ? k0b : (l1 ? j : k1b);
        e0b = l0 ? dv : e0b;               k0b = l0 ? j : k0b;
      }
    }
  }
  pd[seg][yloc][0] = e0a; pd[seg][yloc][1] = e1a; pd[seg][yloc][2] = e2a;
  pi[seg][yloc][0] = k0a; pi[seg][yloc][1] = k1a; pi[seg][yloc][2] = k2a;
  pd[seg][yloc + 1][0] = e0b; pd[seg][yloc + 1][1] = e1b; pd[seg][yloc + 1][2] = e2b;
  pi[seg][yloc + 1][0] = k0b; pi[seg][yloc + 1][1] = k1b; pi[seg][yloc + 1][2] = k2b;
  __syncthreads();

  // 48-way stable merge (seg-ascending) + weights
  if (t < 128) {
    float f0 = 1e30f, f1 = 1e30f, f2 = 1e30f;
    int m0i = 0, m1i = 0, m2i = 0;
#pragma unroll
    for (int s = 0; s < 16; ++s)
#pragma unroll
      for (int c = 0; c < 3; ++c) {
        float d = pd[s][t][c]; int j = pi[s][t][c];
        bool l0 = d < f0, l1 = d < f1, l2 = d < f2;
        f2 = l1 ? f1 : (l2 ? d : f2);  m2i = l1 ? m1i : (l2 ? j : m2i);
        f1 = l0 ? f0 : (l1 ? d : f1);  m1i = l0 ? m0i : (l1 ? j : m1i);
        f0 = l0 ? d : f0;              m0i = l0 ? j : m0i;
      }
    float w0 = 1.0f / (f0 + 1e-8f), w1 = 1.0f / (f1 + 1e-8f), w2 = 1.0f / (f2 + 1e-8f);
    float ws = (w0 + w1) + w2;
    sw[0][t] = w0 / ws; sw[1][t] = w1 / ws; sw[2][t] = w2 / ws;
    si[0][t] = m0i; si[1][t] = m1i; si[2][t] = m2i;
  }
  __syncthreads();

  // ---- gather ----
  const floatx4* xf4 = (const floatx4*)(x_feats + (size_t)b * NXP * CXC);
  const floatx4* yf4 = (const floatx4*)(y_feats + ((size_t)b * NYTOT + chunk * 128) * CYC);
  half_t* fb = A0 + ((size_t)b * NYTOT + chunk * 128) * DIMC;
  {
    const int q = t & 63;
    const int ysub = t >> 6;
    for (int y2 = ysub; y2 < 128; y2 += 16) {
      int j0 = si[0][y2], j1 = si[1][y2], j2 = si[2][y2];
      float a0 = sw[0][y2], a1 = sw[1][y2], a2 = sw[2][y2];
      floatx4 v0 = xf4[(size_t)j0 * 64 + q];
      floatx4 v1 = xf4[(size_t)j1 * 64 + q];
      floatx4 v2 = xf4[(size_t)j2 * 64 + q];
      half4 h;
#pragma unroll
      for (int e = 0; e < 4; ++e)
        h[e] = (half_t)fmaf(v2[e], a2, fmaf(v1[e], a1, v0[e] * a0));
      *(half4*)&fb[(size_t)y2 * DIMC + CYC + q * 4] = h;
    }
  }
  {
    const int q2 = t & 31;
    const int ysub2 = t >> 5;
    for (int y2 = ysub2; y2 < 128; y2 += 32) {
      floatx4 v = yf4[(size_t)y2 * 32 + q2];
      half4 h;
#pragma unroll
      for (int e = 0; e < 4; ++e) h[e] = (half_t)v[e];
      *(half4*)&fb[(size_t)y2 * DIMC + q2 * 4] = h;
    }
  }
}

// ---------------- GEMM 256x128, 2-phase pipelined (round-11 verified) ----
// Only change vs r11: wave-uniform ss index readfirstlane'd -> s_load.
template<int K, int O, int NTN, bool BN>
__global__ __launch_bounds__(512) void gemm256p(
    const half_t* __restrict__ A, const half_t* __restrict__ Wh,
    const float* __restrict__ bias, half_t* __restrict__ C,
    float* __restrict__ sums, const float* __restrict__ ssA) {
  __shared__ __align__(16) short As[16][2][512];     // 32 KB (single buf)
  __shared__ __align__(16) short Bs[2][8][2][512];   // 32 KB (double buf)
  __shared__ float stats[4][2][128];                 // 4 KB
  constexpr int NWG = (MTOT / 256) * NTN;            // multiple of 8
  constexpr int NT = K / 64;
  const int lin = (blockIdx.x & 7) * (NWG >> 3) + (blockIdx.x >> 3);
  const int m0 = (lin / NTN) * 256;
  const int n0 = (lin % NTN) * 128;
  const int tid = threadIdx.x;
  const int lane = tid & 63;
  const int wid = tid >> 6;            // 0..7
  const int wm = wid >> 1, wn = wid & 1;
  const int lm = lane & 15;
  const int lk = (lane >> 4) * 8;
  const int r = tid & 255;             // A-stage row
  const int hh = tid >> 8;             // A-stage k-half (wave-uniform)
  floatx4 acc[4][4] = {};
  half8 in[4];

  // prologue: B(0) -> Bs[0]; A(0) -> regs
#pragma unroll
  for (int c = 0; c < 2; ++c) {
    int id = wid * 2 + c;              // 0..15 (wave-uniform)
    int sub = id >> 1, ks = id & 1;
    const half_t* src = Wh + (size_t)(n0 + sub * 16 + lm) * K + (ks * 32 + lk);
    __builtin_amdgcn_global_load_lds(
        (const __attribute__((address_space(1))) void*)src,
        (__attribute__((address_space(3))) void*)&Bs[0][sub][ks][0], 16, 0, 0);
  }
  {
    const half_t* arow = A + (size_t)(m0 + r) * K + hh * 32;
#pragma unroll
    for (int g = 0; g < 4; ++g) in[g] = *(const half8*)&arow[g * 8];
  }
  int cur = 0;

  for (int t = 0; t < NT; ++t) {
    const int k0 = t * 64;
    __syncthreads();                   // (A) As free; prev-iter vmem drained
#pragma unroll
    for (int g = 0; g < 4; ++g) {
      half8 h;
      if constexpr (BN) {
        int kcu = __builtin_amdgcn_readfirstlane(k0 + hh * 32 + g * 8);
#pragma unroll
        for (int e = 0; e < 8; ++e) {
          float f = fmaxf((float)in[g][e] * ssA[kcu + e] + ssA[K + kcu + e], 0.f);
          h[e] = (half_t)f;
        }
      } else {
        h = in[g];
      }
      *(half8*)&As[r >> 4][hh][(g * 16 + (r & 15)) * 8] = h;
    }
    __syncthreads();                   // (B) As + Bs[cur] ready
    if (t + 1 < NT) {
      const int k1 = k0 + 64;
#pragma unroll
      for (int c = 0; c < 2; ++c) {    // B(t+1) -> Bs[cur^1]
        int id = wid * 2 + c;
        int sub = id >> 1, ks = id & 1;
        const half_t* src = Wh + (size_t)(n0 + sub * 16 + lm) * K + (k1 + ks * 32 + lk);
        __builtin_amdgcn_global_load_lds(
            (const __attribute__((address_space(1))) void*)src,
            (__attribute__((address_space(3))) void*)&Bs[cur ^ 1][sub][ks][0], 16, 0, 0);
      }
      const half_t* arow = A + (size_t)(m0 + r) * K + k1 + hh * 32;
#pragma unroll
      for (int g = 0; g < 4; ++g) in[g] = *(const half8*)&arow[g * 8];
    }
    // compute tile t (latency of the new loads hides under this)
#pragma unroll
    for (int ks = 0; ks < 2; ++ks) {
      half8 af[4], bfm[4];
#pragma unroll
      for (int i = 0; i < 4; ++i) af[i] = *(const half8*)&As[wm * 4 + i][ks][lane * 8];
#pragma unroll
      for (int j = 0; j < 4; ++j) bfm[j] = *(const half8*)&Bs[cur][wn * 4 + j][ks][lane * 8];
#pragma unroll
      for (int i = 0; i < 4; ++i)
#pragma unroll
        for (int j = 0; j < 4; ++j)
          acc[i][j] = __builtin_amdgcn_mfma_f32_16x16x32_f16(af[i], bfm[j], acc[i][j], 0, 0, 0);
    }
    cur ^= 1;
  }

  // epilogue: C/D layout col=lane&15, row=(lane>>4)*4+rr
  float ps[4], pq[4];
#pragma unroll
  for (int j = 0; j < 4; ++j) {
    int nn = n0 + wn * 64 + j * 16 + lm;
    float bv = bias[nn];
    float psum = 0.f, psq = 0.f;
#pragma unroll
    for (int i = 0; i < 4; ++i) {
      int mr = m0 + wm * 64 + i * 16 + (lane >> 4) * 4;
#pragma unroll
      for (int rr = 0; rr < 4; ++rr) {
        float z = acc[i][j][rr] + bv;
        C[(size_t)(mr + rr) * O + nn] = (half_t)z;
        psum += z; psq += z * z;
      }
    }
    psum += __shfl_xor(psum, 16, 64); psq += __shfl_xor(psq, 16, 64);
    psum += __shfl_xor(psum, 32, 64); psq += __shfl_xor(psq, 32, 64);
    ps[j] = psum; pq[j] = psq;
  }
  __syncthreads();                     // all MFMA/LDS reads done
  if ((lane >> 4) == 0) {
#pragma unroll
    for (int j = 0; j < 4; ++j) {
      int ch = wn * 64 + j * 16 + lm;  // 0..127, disjoint per (wn,j)
      stats[wm][0][ch] = ps[j];
      stats[wm][1][ch] = pq[j];
    }
  }
  __syncthreads();
  if (tid < 256) {
    int s = tid >> 7, ch = tid & 127;
    float v = ((stats[0][s][ch] + stats[1][s][ch]) + stats[2][s][ch]) + stats[3][s][ch];
    atomicAdd(&sums[(s ? O : 0) + n0 + ch], v);
  }
}

// ---------------- GEMM 128x128, 2-phase pipelined (gemm3, TOUT) ----------
template<int K, int O, bool BN, bool TOUT>
__global__ __launch_bounds__(256) void gemm128p(
    const half_t* __restrict__ A, const half_t* __restrict__ Wh,
    const float* __restrict__ bias, half_t* __restrict__ C,
    float* __restrict__ sums, const float* __restrict__ ssA) {
  __shared__ __align__(16) short As[8][2][512];      // 16 KB
  __shared__ __align__(16) short Bs[2][8][2][512];   // 32 KB
  __shared__ float stats[2][2][128];                 // 2 KB
  constexpr int NT = K / 64;
  const int m0 = blockIdx.x * 128;
  const int n0 = blockIdx.y * 128;
  const int tid = threadIdx.x;
  const int lane = tid & 63;
  const int wid = tid >> 6;
  const int wm = wid >> 1, wn = wid & 1;
  const int lm = lane & 15;
  const int lk = (lane >> 4) * 8;
  const int r = tid & 127;
  const int hh = tid >> 7;             // wave-uniform
  floatx4 acc[4][4] = {};
  half8 in[4];

#pragma unroll
  for (int c = 0; c < 4; ++c) {
    int id = wid * 4 + c;              // 0..15
    int sub = id >> 1, ks = id & 1;
    const half_t* src = Wh + (size_t)(n0 + sub * 16 + lm) * K + (ks * 32 + lk);
    __builtin_amdgcn_global_load_lds(
        (const __attribute__((address_space(1))) void*)src,
        (__attribute__((address_space(3))) void*)&Bs[0][sub][ks][0], 16, 0, 0);
  }
  {
    const half_t* arow = A + (size_t)(m0 + r) * K + hh * 32;
#pragma unroll
    for (int g = 0; g < 4; ++g) in[g] = *(const half8*)&arow[g * 8];
  }
  int cur = 0;

  for (int t = 0; t < NT; ++t) {
    const int k0 = t * 64;
    __syncthreads();                   // (A)
#pragma unroll
    for (int g = 0; g < 4; ++g) {
      half8 h;
      if constexpr (BN) {
        int kcu = __builtin_amdgcn_readfirstlane(k0 + hh * 32 + g * 8);
#pragma unroll
        for (int e = 0; e < 8; ++e) {
          float f = fmaxf((float)in[g][e] * ssA[kcu + e] + ssA[K + kcu + e], 0.f);
          h[e] = (half_t)f;
        }
      } else {
        h = in[g];
      }
      *(half8*)&As[r >> 4][hh][(g * 16 + (r & 15)) * 8] = h;
    }
    __syncthreads();                   // (B)
    if (t + 1 < NT) {
      const int k1 = k0 + 64;
#pragma unroll
      for (int c = 0; c < 4; ++c) {
        int id = wid * 4 + c;
        int sub = id >> 1, ks = id & 1;
        const half_t* src = Wh + (size_t)(n0 + sub * 16 + lm) * K + (k1 + ks * 32 + lk);
        __builtin_amdgcn_global_load_lds(
            (const __attribute__((address_space(1))) void*)src,
            (__attribute__((address_space(3))) void*)&Bs[cur ^ 1][sub][ks][0], 16, 0, 0);
      }
      const half_t* arow = A + (size_t)(m0 + r) * K + k1 + hh * 32;
#pragma unroll
      for (int g = 0; g < 4; ++g) in[g] = *(const half8*)&arow[g * 8];
    }
#pragma unroll
    for (int ks = 0; ks < 2; ++ks) {
      half8 af[4], bfm[4];
#pragma unroll
      for (int i = 0; i < 4; ++i) af[i] = *(const half8*)&As[wm * 4 + i][ks][lane * 8];
#pragma unroll
      for (int j = 0; j < 4; ++j) bfm[j] = *(const half8*)&Bs[cur][wn * 4 + j][ks][lane * 8];
#pragma unroll
      for (int i = 0; i < 4; ++i)
#pragma unroll
        for (int j = 0; j < 4; ++j)
          acc[i][j] = __builtin_amdgcn_mfma_f32_16x16x32_f16(af[i], bfm[j], acc[i][j], 0, 0, 0);
    }
    cur ^= 1;
  }

  const int bb = m0 >> 14;             // block-uniform batch (TOUT)
  const int nbase = (m0 & (NYTOT - 1)) + wm * 64 + (lane >> 4) * 4;
  float ps[4], pq[4];
#pragma unroll
  for (int j = 0; j < 4; ++j) {
    int nn = n0 + wn * 64 + j * 16 + lm;
    float bv = bias[nn];
    float psum = 0.f, psq = 0.f;
#pragma unroll
    for (int i = 0; i < 4; ++i) {
      half4 hv;
#pragma unroll
      for (int rr = 0; rr < 4; ++rr) {
        float z = acc[i][j][rr] + bv;
        hv[rr] = (half_t)z;
        psum += z; psq += z * z;
      }
      if constexpr (TOUT) {
        *(half4*)&C[((size_t)(bb * O + nn)) * NYTOT + nbase + i * 16] = hv;
      } else {
        int mr = m0 + wm * 64 + i * 16 + (lane >> 4) * 4;
#pragma unroll
        for (int rr = 0; rr < 4; ++rr)
          C[(size_t)(mr + rr) * O + nn] = hv[rr];
      }
    }
    psum += __shfl_xor(psum, 16, 64); psq += __shfl_xor(psq, 16, 64);
    psum += __shfl_xor(psum, 32, 64); psq += __shfl_xor(psq, 32, 64);
    ps[j] = psum; pq[j] = psq;
  }
  __syncthreads();
  if ((lane >> 4) == 0) {
#pragma unroll
    for (int j = 0; j < 4; ++j) {
      int ch = wn * 64 + j * 16 + lm;
      stats[wm][0][ch] = ps[j];
      stats[wm][1][ch] = pq[j];
    }
  }
  __syncthreads();
  if (tid < 256) {
    int s = tid >> 7, ch = tid & 127;
    float v = stats[0][s][ch] + stats[1][s][ch];
    atomicAdd(&sums[(s ? O : 0) + n0 + ch], v);
  }
}

// ---------------- finalize BN scale/shift ----------
__global__ void finalize_kernel(const float* __restrict__ sums, const float* __restrict__ g,
                                const float* __restrict__ be, float* __restrict__ ss, int O) {
  int c = threadIdx.x;
  if (c < O) {
    const float invN = 1.0f / 65536.0f;
    float mean = sums[c] * invN;
    float var = sums[O + c] * invN - mean * mean;
    float sc = g[c] / sqrtf(var + 1e-5f);
    float sh = be[c] - mean * sc;
    if (!isfinite(sc) || !isfinite(sh)) { sc = 1.0f; sh = 0.0f; }
    ss[c] = sc;
    ss[O + c] = sh;
  }
}

// ---------------- final: elementwise BN3+ReLU fp16->fp32 ----------------
__global__ __launch_bounds__(256) void bnfin_kernel(
    const half_t* __restrict__ Z, const float* __restrict__ ss,
    float* __restrict__ out) {
  size_t i = (size_t)blockIdx.x * 256 + threadIdx.x;   // HF8 index
  int c = (int)((i * 8) >> 14) & 127;
  float sc = ss[c], sh = ss[128 + c];
  HF8 v = ((const HF8*)Z)[i];
  floatx4 o0, o1;
#pragma unroll
  for (int e = 0; e < 4; ++e) {
    o0[e] = fmaxf((float)v.h[e] * sc + sh, 0.f);
    o1[e] = fmaxf((float)v.h[4 + e] * sc + sh, 0.f);
  }
  ((floatx4*)out)[i * 2] = o0;
  ((floatx4*)out)[i * 2 + 1] = o1;
}

extern "C" void kernel_launch(void* const* d_in, const int* in_sizes, int n_in,
                              void* d_out, int out_size, void* d_ws, size_t ws_size,
                              hipStream_t stream) {
  const float* y_points = (const float*)d_in[0];
  const float* y_feats  = (const float*)d_in[1];
  const float* x_points = (const float*)d_in[2];
  const float* x_feats  = (const float*)d_in[3];
  const float* W1 = (const float*)d_in[4];  const float* b1 = (const float*)d_in[5];
  const float* g1 = (const float*)d_in[6];  const float* be1 = (const float*)d_in[7];
  const float* W2 = (const float*)d_in[8];  const float* b2 = (const float*)d_in[9];
  const float* g2 = (const float*)d_in[10]; const float* be2 = (const float*)d_in[11];
  const float* W3 = (const float*)d_in[12]; const float* b3 = (const float*)d_in[13];
  const float* g3 = (const float*)d_in[14]; const float* be3 = (const float*)d_in[15];

  // workspace layout (identical bounds to round 11 — no new bytes):
  //   [0, 50.33MB)        : A0 fp16 [M,384]  (later aliased by z2)
  //   [50.33MB, 117.44MB) : z1 fp16 [M,512]  (xq pre-gemm1; z3T after gemm2)
  //   [117.44MB, ...)     : BN stats (st[0..3583])
  // d_out (33.5 MB) doubles as scratch for fp16 weights until bnfin.
  char* ws = (char*)d_ws;
  half_t* A0 = (half_t*)ws;                      // 65536*384*2 = 50,331,648
  half_t* z1 = (half_t*)(ws + 50331648);         // 65536*512*2 = 67,108,864
  half_t* z2 = (half_t*)ws;                      // alias A0 (dead after gemm1)
  half_t* z3T = (half_t*)(ws + 50331648);        // alias z1 (dead after gemm2)
  float4* xq = (float4*)(ws + 50331648);         // alias z1 head (dead pre-gemm1)
  float* st = (float*)(ws + 117440512);
  // st floats: sum1/sq1 @0 (1024), sum2/sq2 @1024 (512), sum3/sq3 @1536 (256),
  //            ss1 @1792 (1024), ss2 @2816 (512), ss3 @3328 (256)
  half_t* W1h = (half_t*)d_out;                  // 512*384  = 196608 halfs
  half_t* W2h = W1h + 196608;                    // 256*512  = 131072 halfs
  half_t* W3h = W1h + 327680;                    // 128*256  =  32768 halfs

  prep_kernel<<<417, 256, 0, stream>>>(x_points, xq, W1, W2, W3, W1h, st);
  interp_kernel<<<512, 1024, 0, stream>>>(y_points, y_feats, x_feats, xq, A0);

  // gemm1: 256x128 tile, 1024 blocks (XCD-swizzled, n-fastest), pipelined
  gemm256p<384, 512, 4, false><<<1024, 512, 0, stream>>>(A0, W1h, b1, z1, st + 0, nullptr);
  finalize_kernel<<<1, 512, 0, stream>>>(st + 0, g1, be1, st + 1792, 512);

  // gemm2: BN1+ReLU fused into A-staging, pipelined
  gemm256p<512, 256, 2, true><<<512, 512, 0, stream>>>(z1, W2h, b2, z2, st + 1024, st + 1792);
  finalize_kernel<<<1, 256, 0, stream>>>(st + 1024, g2, be2, st + 2816, 256);

  // gemm3: BN2+ReLU fused, pipelined, TOUT layout
  gemm128p<256, 128, true, true><<<dim3(512, 1), 256, 0, stream>>>(z2, W3h, b3, z3T, st + 1536, st + 2816);
  finalize_kernel<<<1, 128, 0, stream>>>(st + 1536, g3, be3, st + 3328, 128);

  // final: elementwise BN3+ReLU fp16->fp32 (no transpose needed)
  bnfin_kernel<<<4096, 256, 0, stream>>>(z3T, st + 3328, (float*)d_out);
}

// Round 14
// 434.994 us; speedup vs baseline: 1.1036x; 1.0154x over previous
//
#include <hip/hip_runtime.h>

#define NYTOT 16384
#define NXP 4096
#define MTOT 65536   // B * NY
#define CYC 128
#define CXC 256
#define DIMC 384

typedef __attribute__((ext_vector_type(8))) _Float16 half8;
typedef __attribute__((ext_vector_type(4))) _Float16 half4;
typedef __attribute__((ext_vector_type(4))) float floatx4;
typedef __attribute__((ext_vector_type(2))) float floatx2;

using half_t = _Float16;

struct alignas(16) HF8 { half_t h[8]; };

__device__ __forceinline__ float fmed3(float a, float b, float c) {
  return __builtin_amdgcn_fmed3f(a, b, c);
}

// ---------------- K0: merged prep — xq table + fp16 weights + st zero ----
__global__ __launch_bounds__(256) void prep_kernel(
    const float* __restrict__ x_points, float4* __restrict__ xq,
    const float* __restrict__ W1, const float* __restrict__ W2,
    const float* __restrict__ W3, half_t* __restrict__ wout,
    float* __restrict__ st) {
#pragma clang fp contract(off)
  const int bid = blockIdx.x;
  if (bid == 416) {
    int t = threadIdx.x;
    for (int k = t; k < 1792; k += 256) st[k] = 0.f;
    return;
  }
  if (bid < 64) {
    int j = bid * 256 + threadIdx.x;          // 0..16383
    int b = j >> 12, jj = j & 4095;
    const float* p = x_points + (size_t)b * NXP * 3 + 3 * jj;
    float x0 = p[0], x1 = p[1], x2 = p[2];
    float sx = (x0 * x0 + x1 * x1) + x2 * x2; // ref order
    float4 v; v.x = x0; v.y = x1; v.z = x2; v.w = sx;
    xq[j] = v;
  } else {
    int i = (bid - 64) * 256 + threadIdx.x;   // float4 index, 0..90111
    const float* src; half_t* dst; int j;
    if (i < 49152)      { src = W1; dst = wout;          j = i; }
    else if (i < 81920) { src = W2; dst = wout + 196608; j = i - 49152; }
    else                { src = W3; dst = wout + 327680; j = i - 81920; }
    floatx4 v = ((const floatx4*)src)[j];
    half4 h;
#pragma unroll
    for (int e = 0; e < 4; ++e) h[e] = (half_t)v[e];
    ((half4*)dst)[j] = h;
  }
}

// ---------------- K1: 3-NN interpolation (round-5/8/10 verified exact) ---
// unroll-16 probe REVERTED (r13: +6us, +14MB writes, SGPR 80 — unroll 8 is
// the verified optimum).
__global__ __launch_bounds__(1024, 8) void interp_kernel(
    const float* __restrict__ y_points, const float* __restrict__ y_feats,
    const float* __restrict__ x_feats, const float4* __restrict__ xq,
    half_t* __restrict__ A0) {
#pragma clang fp contract(off)
  __shared__ float pd[16][128][3];        // 24 KB partial dists
  __shared__ int   pi[16][128][3];        // 24 KB partial idx
  __shared__ float t2s[128];
  __shared__ float sw[3][128];
  __shared__ int   si[3][128];
  const int b = blockIdx.x >> 7;
  const int chunk = blockIdx.x & 127;
  const int t = threadIdx.x;
  const int lane = t & 63;
  const int seg = t >> 6;                 // wave id == segment, 0..15
  const int yloc = lane << 1;             // my 2 y's: yloc, yloc+1

  const float* yp = y_points + ((size_t)b * NYTOT + chunk * 128 + yloc) * 3;
  floatx2 Y0 = {yp[0], yp[3]};
  floatx2 Y1 = {yp[1], yp[4]};
  floatx2 Y2 = {yp[2], yp[5]};
  floatx2 SY = (Y0 * Y0 + Y1 * Y1) + Y2 * Y2;       // ref order per element

  const float4* xqs = xq + (size_t)b * NXP;
  const int jb = __builtin_amdgcn_readfirstlane(seg * 256);

  // ---- phase 1: value-only top-3 per (seg, y) via med3/min ----
  floatx2 D0 = {1e30f, 1e30f}, D1 = D0, D2 = D0;
#pragma unroll 8
  for (int jj = 0; jj < 256; ++jj) {
    float4 p = xqs[jb + jj];                        // wave-uniform load
    floatx2 inner = (Y0 * p.x + Y1 * p.y) + Y2 * p.z;
    floatx2 d = (SY + p.w) - 2.0f * inner;
    D2.x = fmed3(d.x, D1.x, D2.x);  D2.y = fmed3(d.y, D1.y, D2.y);
    D1.x = fmed3(d.x, D0.x, D1.x);  D1.y = fmed3(d.y, D0.y, D1.y);
    D0.x = fminf(d.x, D0.x);        D0.y = fminf(d.y, D0.y);
  }
  pd[seg][yloc][0] = D0.x; pd[seg][yloc][1] = D1.x; pd[seg][yloc][2] = D2.x;
  pd[seg][yloc + 1][0] = D0.y; pd[seg][yloc + 1][1] = D1.y; pd[seg][yloc + 1][2] = D2.y;
  __syncthreads();

  // global 3rd-smallest per y
  if (t < 128) {
    float m0 = 1e30f, m1 = 1e30f, m2 = 1e30f;
#pragma unroll
    for (int s = 0; s < 16; ++s)
#pragma unroll
      for (int c = 0; c < 3; ++c) {
        float v = pd[s][t][c];
        m2 = fmed3(v, m1, m2);
        m1 = fmed3(v, m0, m1);
        m0 = fminf(v, m0);
      }
    t2s[t] = m2;
  }
  __syncthreads();

  // ---- phase 2: gated stable index recovery ----
  const float t2a = t2s[yloc], t2b = t2s[yloc + 1];
  const float tmax = fmaxf(t2a, t2b);
  float e0a = 1e30f, e1a = 1e30f, e2a = 1e30f; int k0a = 0, k1a = 0, k2a = 0;
  float e0b = 1e30f, e1b = 1e30f, e2b = 1e30f; int k0b = 0, k1b = 0, k2b = 0;
#pragma unroll 4
  for (int jj = 0; jj < 256; ++jj) {
    float4 p = xqs[jb + jj];
    floatx2 inner = (Y0 * p.x + Y1 * p.y) + Y2 * p.z;
    floatx2 d = (SY + p.w) - 2.0f * inner;
    if (fminf(d.x, d.y) <= tmax) {                  // rare
      int j = jb + jj;
      {
        float dv = d.x;
        bool l0 = dv < e0a, l1 = dv < e1a, l2 = dv < e2a;
        e2a = l1 ? e1a : (l2 ? dv : e2a);  k2a = l1 ? k1a : (l2 ? j : k2a);
        e1a = l0 ? e0a : (l1 ? dv : e1a);  k1a = l0 ? k0a : (l1 ? j : k1a);
        e0a = l0 ? dv : e0a;               k0a = l0 ? j : k0a;
      }
      {
        float dv = d.y;
        bool l0 = dv < e0b, l1 = dv < e1b, l2 = dv < e2b;
        e2b = l1 ? e1b : (l2 ? dv : e2b);  k2b = l1 ? k1b : (l2 ? j : k2b);
        e1b = l0 ? e0b : (l1 ? dv : e1b);  k1b = l0 ? k0b : (l1 ? j : k1b);
        e0b = l0 ? dv : e0b;               k0b = l0 ? j : k0b;
      }
    }
  }
  pd[seg][yloc][0] = e0a; pd[seg][yloc][1] = e1a; pd[seg][yloc][2] = e2a;
  pi[seg][yloc][0] = k0a; pi[seg][yloc][1] = k1a; pi[seg][yloc][2] = k2a;
  pd[seg][yloc + 1][0] = e0b; pd[seg][yloc + 1][1] = e1b; pd[seg][yloc + 1][2] = e2b;
  pi[seg][yloc + 1][0] = k0b; pi[seg][yloc + 1][1] = k1b; pi[seg][yloc + 1][2] = k2b;
  __syncthreads();

  // 48-way stable merge (seg-ascending) + weights
  if (t < 128) {
    float f0 = 1e30f, f1 = 1e30f, f2 = 1e30f;
    int m0i = 0, m1i = 0, m2i = 0;
#pragma unroll
    for (int s = 0; s < 16; ++s)
#pragma unroll
      for (int c = 0; c < 3; ++c) {
        float d = pd[s][t][c]; int j = pi[s][t][c];
        bool l0 = d < f0, l1 = d < f1, l2 = d < f2;
        f2 = l1 ? f1 : (l2 ? d : f2);  m2i = l1 ? m1i : (l2 ? j : m2i);
        f1 = l0 ? f0 : (l1 ? d : f1);  m1i = l0 ? m0i : (l1 ? j : m1i);
        f0 = l0 ? d : f0;              m0i = l0 ? j : m0i;
      }
    float w0 = 1.0f / (f0 + 1e-8f), w1 = 1.0f / (f1 + 1e-8f), w2 = 1.0f / (f2 + 1e-8f);
    float ws = (w0 + w1) + w2;
    sw[0][t] = w0 / ws; sw[1][t] = w1 / ws; sw[2][t] = w2 / ws;
    si[0][t] = m0i; si[1][t] = m1i; si[2][t] = m2i;
  }
  __syncthreads();

  // ---- gather ----
  const floatx4* xf4 = (const floatx4*)(x_feats + (size_t)b * NXP * CXC);
  const floatx4* yf4 = (const floatx4*)(y_feats + ((size_t)b * NYTOT + chunk * 128) * CYC);
  half_t* fb = A0 + ((size_t)b * NYTOT + chunk * 128) * DIMC;
  {
    const int q = t & 63;
    const int ysub = t >> 6;
    for (int y2 = ysub; y2 < 128; y2 += 16) {
      int j0 = si[0][y2], j1 = si[1][y2], j2 = si[2][y2];
      float a0 = sw[0][y2], a1 = sw[1][y2], a2 = sw[2][y2];
      floatx4 v0 = xf4[(size_t)j0 * 64 + q];
      floatx4 v1 = xf4[(size_t)j1 * 64 + q];
      floatx4 v2 = xf4[(size_t)j2 * 64 + q];
      half4 h;
#pragma unroll
      for (int e = 0; e < 4; ++e)
        h[e] = (half_t)fmaf(v2[e], a2, fmaf(v1[e], a1, v0[e] * a0));
      *(half4*)&fb[(size_t)y2 * DIMC + CYC + q * 4] = h;
    }
  }
  {
    const int q2 = t & 31;
    const int ysub2 = t >> 5;
    for (int y2 = ysub2; y2 < 128; y2 += 32) {
      floatx4 v = yf4[(size_t)y2 * 32 + q2];
      half4 h;
#pragma unroll
      for (int e = 0; e < 4; ++e) h[e] = (half_t)v[e];
      *(half4*)&fb[(size_t)y2 * DIMC + q2 * 4] = h;
    }
  }
}

// ---------------- GEMM 256x128, 2-phase pipelined (round-13 verified) ----
template<int K, int O, int NTN, bool BN>
__global__ __launch_bounds__(512) void gemm256p(
    const half_t* __restrict__ A, const half_t* __restrict__ Wh,
    const float* __restrict__ bias, half_t* __restrict__ C,
    float* __restrict__ sums, const float* __restrict__ ssA) {
  __shared__ __align__(16) short As[16][2][512];     // 32 KB (single buf)
  __shared__ __align__(16) short Bs[2][8][2][512];   // 32 KB (double buf)
  __shared__ float stats[4][2][128];                 // 4 KB
  constexpr int NWG = (MTOT / 256) * NTN;            // multiple of 8
  constexpr int NT = K / 64;
  const int lin = (blockIdx.x & 7) * (NWG >> 3) + (blockIdx.x >> 3);
  const int m0 = (lin / NTN) * 256;
  const int n0 = (lin % NTN) * 128;
  const int tid = threadIdx.x;
  const int lane = tid & 63;
  const int wid = tid >> 6;            // 0..7
  const int wm = wid >> 1, wn = wid & 1;
  const int lm = lane & 15;
  const int lk = (lane >> 4) * 8;
  const int r = tid & 255;             // A-stage row
  const int hh = tid >> 8;             // A-stage k-half (wave-uniform)
  floatx4 acc[4][4] = {};
  half8 in[4];

  // prologue: B(0) -> Bs[0]; A(0) -> regs
#pragma unroll
  for (int c = 0; c < 2; ++c) {
    int id = wid * 2 + c;              // 0..15 (wave-uniform)
    int sub = id >> 1, ks = id & 1;
    const half_t* src = Wh + (size_t)(n0 + sub * 16 + lm) * K + (ks * 32 + lk);
    __builtin_amdgcn_global_load_lds(
        (const __attribute__((address_space(1))) void*)src,
        (__attribute__((address_space(3))) void*)&Bs[0][sub][ks][0], 16, 0, 0);
  }
  {
    const half_t* arow = A + (size_t)(m0 + r) * K + hh * 32;
#pragma unroll
    for (int g = 0; g < 4; ++g) in[g] = *(const half8*)&arow[g * 8];
  }
  int cur = 0;

  for (int t = 0; t < NT; ++t) {
    const int k0 = t * 64;
    __syncthreads();                   // (A) As free; prev-iter vmem drained
#pragma unroll
    for (int g = 0; g < 4; ++g) {
      half8 h;
      if constexpr (BN) {
        int kcu = __builtin_amdgcn_readfirstlane(k0 + hh * 32 + g * 8);
#pragma unroll
        for (int e = 0; e < 8; ++e) {
          float f = fmaxf((float)in[g][e] * ssA[kcu + e] + ssA[K + kcu + e], 0.f);
          h[e] = (half_t)f;
        }
      } else {
        h = in[g];
      }
      *(half8*)&As[r >> 4][hh][(g * 16 + (r & 15)) * 8] = h;
    }
    __syncthreads();                   // (B) As + Bs[cur] ready
    if (t + 1 < NT) {
      const int k1 = k0 + 64;
#pragma unroll
      for (int c = 0; c < 2; ++c) {    // B(t+1) -> Bs[cur^1]
        int id = wid * 2 + c;
        int sub = id >> 1, ks = id & 1;
        const half_t* src = Wh + (size_t)(n0 + sub * 16 + lm) * K + (k1 + ks * 32 + lk);
        __builtin_amdgcn_global_load_lds(
            (const __attribute__((address_space(1))) void*)src,
            (__attribute__((address_space(3))) void*)&Bs[cur ^ 1][sub][ks][0], 16, 0, 0);
      }
      const half_t* arow = A + (size_t)(m0 + r) * K + k1 + hh * 32;
#pragma unroll
      for (int g = 0; g < 4; ++g) in[g] = *(const half8*)&arow[g * 8];
    }
    // compute tile t (latency of the new loads hides under this)
#pragma unroll
    for (int ks = 0; ks < 2; ++ks) {
      half8 af[4], bfm[4];
#pragma unroll
      for (int i = 0; i < 4; ++i) af[i] = *(const half8*)&As[wm * 4 + i][ks][lane * 8];
#pragma unroll
      for (int j = 0; j < 4; ++j) bfm[j] = *(const half8*)&Bs[cur][wn * 4 + j][ks][lane * 8];
#pragma unroll
      for (int i = 0; i < 4; ++i)
#pragma unroll
        for (int j = 0; j < 4; ++j)
          acc[i][j] = __builtin_amdgcn_mfma_f32_16x16x32_f16(af[i], bfm[j], acc[i][j], 0, 0, 0);
    }
    cur ^= 1;
  }

  // epilogue: C/D layout col=lane&15, row=(lane>>4)*4+rr
  float ps[4], pq[4];
#pragma unroll
  for (int j = 0; j < 4; ++j) {
    int nn = n0 + wn * 64 + j * 16 + lm;
    float bv = bias[nn];
    float psum = 0.f, psq = 0.f;
#pragma unroll
    for (int i = 0; i < 4; ++i) {
      int mr = m0 + wm * 64 + i * 16 + (lane >> 4) * 4;
#pragma unroll
      for (int rr = 0; rr < 4; ++rr) {
        float z = acc[i][j][rr] + bv;
        C[(size_t)(mr + rr) * O + nn] = (half_t)z;
        psum += z; psq += z * z;
      }
    }
    psum += __shfl_xor(psum, 16, 64); psq += __shfl_xor(psq, 16, 64);
    psum += __shfl_xor(psum, 32, 64); psq += __shfl_xor(psq, 32, 64);
    ps[j] = psum; pq[j] = psq;
  }
  __syncthreads();                     // all MFMA/LDS reads done
  if ((lane >> 4) == 0) {
#pragma unroll
    for (int j = 0; j < 4; ++j) {
      int ch = wn * 64 + j * 16 + lm;  // 0..127, disjoint per (wn,j)
      stats[wm][0][ch] = ps[j];
      stats[wm][1][ch] = pq[j];
    }
  }
  __syncthreads();
  if (tid < 256) {
    int s = tid >> 7, ch = tid & 127;
    float v = ((stats[0][s][ch] + stats[1][s][ch]) + stats[2][s][ch]) + stats[3][s][ch];
    atomicAdd(&sums[(s ? O : 0) + n0 + ch], v);
  }
}

// ---------------- GEMM 128x128, 2-phase pipelined (gemm3, TOUT) ----------
template<int K, int O, bool BN, bool TOUT>
__global__ __launch_bounds__(256) void gemm128p(
    const half_t* __restrict__ A, const half_t* __restrict__ Wh,
    const float* __restrict__ bias, half_t* __restrict__ C,
    float* __restrict__ sums, const float* __restrict__ ssA) {
  __shared__ __align__(16) short As[8][2][512];      // 16 KB
  __shared__ __align__(16) short Bs[2][8][2][512];   // 32 KB
  __shared__ float stats[2][2][128];                 // 2 KB
  constexpr int NT = K / 64;
  const int m0 = blockIdx.x * 128;
  const int n0 = blockIdx.y * 128;
  const int tid = threadIdx.x;
  const int lane = tid & 63;
  const int wid = tid >> 6;
  const int wm = wid >> 1, wn = wid & 1;
  const int lm = lane & 15;
  const int lk = (lane >> 4) * 8;
  const int r = tid & 127;
  const int hh = tid >> 7;             // wave-uniform
  floatx4 acc[4][4] = {};
  half8 in[4];

#pragma unroll
  for (int c = 0; c < 4; ++c) {
    int id = wid * 4 + c;              // 0..15
    int sub = id >> 1, ks = id & 1;
    const half_t* src = Wh + (size_t)(n0 + sub * 16 + lm) * K + (ks * 32 + lk);
    __builtin_amdgcn_global_load_lds(
        (const __attribute__((address_space(1))) void*)src,
        (__attribute__((address_space(3))) void*)&Bs[0][sub][ks][0], 16, 0, 0);
  }
  {
    const half_t* arow = A + (size_t)(m0 + r) * K + hh * 32;
#pragma unroll
    for (int g = 0; g < 4; ++g) in[g] = *(const half8*)&arow[g * 8];
  }
  int cur = 0;

  for (int t = 0; t < NT; ++t) {
    const int k0 = t * 64;
    __syncthreads();                   // (A)
#pragma unroll
    for (int g = 0; g < 4; ++g) {
      half8 h;
      if constexpr (BN) {
        int kcu = __builtin_amdgcn_readfirstlane(k0 + hh * 32 + g * 8);
#pragma unroll
        for (int e = 0; e < 8; ++e) {
          float f = fmaxf((float)in[g][e] * ssA[kcu + e] + ssA[K + kcu + e], 0.f);
          h[e] = (half_t)f;
        }
      } else {
        h = in[g];
      }
      *(half8*)&As[r >> 4][hh][(g * 16 + (r & 15)) * 8] = h;
    }
    __syncthreads();                   // (B)
    if (t + 1 < NT) {
      const int k1 = k0 + 64;
#pragma unroll
      for (int c = 0; c < 4; ++c) {
        int id = wid * 4 + c;
        int sub = id >> 1, ks = id & 1;
        const half_t* src = Wh + (size_t)(n0 + sub * 16 + lm) * K + (k1 + ks * 32 + lk);
        __builtin_amdgcn_global_load_lds(
            (const __attribute__((address_space(1))) void*)src,
            (__attribute__((address_space(3))) void*)&Bs[cur ^ 1][sub][ks][0], 16, 0, 0);
      }
      const half_t* arow = A + (size_t)(m0 + r) * K + k1 + hh * 32;
#pragma unroll
      for (int g = 0; g < 4; ++g) in[g] = *(const half8*)&arow[g * 8];
    }
#pragma unroll
    for (int ks = 0; ks < 2; ++ks) {
      half8 af[4], bfm[4];
#pragma unroll
      for (int i = 0; i < 4; ++i) af[i] = *(const half8*)&As[wm * 4 + i][ks][lane * 8];
#pragma unroll
      for (int j = 0; j < 4; ++j) bfm[j] = *(const half8*)&Bs[cur][wn * 4 + j][ks][lane * 8];
#pragma unroll
      for (int i = 0; i < 4; ++i)
#pragma unroll
        for (int j = 0; j < 4; ++j)
          acc[i][j] = __builtin_amdgcn_mfma_f32_16x16x32_f16(af[i], bfm[j], acc[i][j], 0, 0, 0);
    }
    cur ^= 1;
  }

  const int bb = m0 >> 14;             // block-uniform batch (TOUT)
  const int nbase = (m0 & (NYTOT - 1)) + wm * 64 + (lane >> 4) * 4;
  float ps[4], pq[4];
#pragma unroll
  for (int j = 0; j < 4; ++j) {
    int nn = n0 + wn * 64 + j * 16 + lm;
    float bv = bias[nn];
    float psum = 0.f, psq = 0.f;
#pragma unroll
    for (int i = 0; i < 4; ++i) {
      half4 hv;
#pragma unroll
      for (int rr = 0; rr < 4; ++rr) {
        float z = acc[i][j][rr] + bv;
        hv[rr] = (half_t)z;
        psum += z; psq += z * z;
      }
      if constexpr (TOUT) {
        *(half4*)&C[((size_t)(bb * O + nn)) * NYTOT + nbase + i * 16] = hv;
      } else {
        int mr = m0 + wm * 64 + i * 16 + (lane >> 4) * 4;
#pragma unroll
        for (int rr = 0; rr < 4; ++rr)
          C[(size_t)(mr + rr) * O + nn] = hv[rr];
      }
    }
    psum += __shfl_xor(psum, 16, 64); psq += __shfl_xor(psq, 16, 64);
    psum += __shfl_xor(psum, 32, 64); psq += __shfl_xor(psq, 32, 64);
    ps[j] = psum; pq[j] = psq;
  }
  __syncthreads();
  if ((lane >> 4) == 0) {
#pragma unroll
    for (int j = 0; j < 4; ++j) {
      int ch = wn * 64 + j * 16 + lm;
      stats[wm][0][ch] = ps[j];
      stats[wm][1][ch] = pq[j];
    }
  }
  __syncthreads();
  if (tid < 256) {
    int s = tid >> 7, ch = tid & 127;
    float v = stats[0][s][ch] + stats[1][s][ch];
    atomicAdd(&sums[(s ? O : 0) + n0 + ch], v);
  }
}

// ---------------- finalize BN scale/shift ----------
__global__ void finalize_kernel(const float* __restrict__ sums, const float* __restrict__ g,
                                const float* __restrict__ be, float* __restrict__ ss, int O) {
  int c = threadIdx.x;
  if (c < O) {
    const float invN = 1.0f / 65536.0f;
    float mean = sums[c] * invN;
    float var = sums[O + c] * invN - mean * mean;
    float sc = g[c] / sqrtf(var + 1e-5f);
    float sh = be[c] - mean * sc;
    if (!isfinite(sc) || !isfinite(sh)) { sc = 1.0f; sh = 0.0f; }
    ss[c] = sc;
    ss[O + c] = sh;
  }
}

// ---------------- final: elementwise BN3+ReLU fp16->fp32 ----------------
__global__ __launch_bounds__(256) void bnfin_kernel(
    const half_t* __restrict__ Z, const float* __restrict__ ss,
    float* __restrict__ out) {
  size_t i = (size_t)blockIdx.x * 256 + threadIdx.x;   // HF8 index
  int c = (int)((i * 8) >> 14) & 127;
  float sc = ss[c], sh = ss[128 + c];
  HF8 v = ((const HF8*)Z)[i];
  floatx4 o0, o1;
#pragma unroll
  for (int e = 0; e < 4; ++e) {
    o0[e] = fmaxf((float)v.h[e] * sc + sh, 0.f);
    o1[e] = fmaxf((float)v.h[4 + e] * sc + sh, 0.f);
  }
  ((floatx4*)out)[i * 2] = o0;
  ((floatx4*)out)[i * 2 + 1] = o1;
}

extern "C" void kernel_launch(void* const* d_in, const int* in_sizes, int n_in,
                              void* d_out, int out_size, void* d_ws, size_t ws_size,
                              hipStream_t stream) {
  const float* y_points = (const float*)d_in[0];
  const float* y_feats  = (const float*)d_in[1];
  const float* x_points = (const float*)d_in[2];
  const float* x_feats  = (const float*)d_in[3];
  const float* W1 = (const float*)d_in[4];  const float* b1 = (const float*)d_in[5];
  const float* g1 = (const float*)d_in[6];  const float* be1 = (const float*)d_in[7];
  const float* W2 = (const float*)d_in[8];  const float* b2 = (const float*)d_in[9];
  const float* g2 = (const float*)d_in[10]; const float* be2 = (const float*)d_in[11];
  const float* W3 = (const float*)d_in[12]; const float* b3 = (const float*)d_in[13];
  const float* g3 = (const float*)d_in[14]; const float* be3 = (const float*)d_in[15];

  // workspace layout (identical bounds to round 11/13 — no new bytes):
  //   [0, 50.33MB)        : A0 fp16 [M,384]  (later aliased by z2)
  //   [50.33MB, 117.44MB) : z1 fp16 [M,512]  (xq pre-gemm1; z3T after gemm2)
  //   [117.44MB, ...)     : BN stats (st[0..3583])
  // d_out (33.5 MB) doubles as scratch for fp16 weights until bnfin.
  char* ws = (char*)d_ws;
  half_t* A0 = (half_t*)ws;                      // 65536*384*2 = 50,331,648
  half_t* z1 = (half_t*)(ws + 50331648);         // 65536*512*2 = 67,108,864
  half_t* z2 = (half_t*)ws;                      // alias A0 (dead after gemm1)
  half_t* z3T = (half_t*)(ws + 50331648);        // alias z1 (dead after gemm2)
  float4* xq = (float4*)(ws + 50331648);         // alias z1 head (dead pre-gemm1)
  float* st = (float*)(ws + 117440512);
  // st floats: sum1/sq1 @0 (1024), sum2/sq2 @1024 (512), sum3/sq3 @1536 (256),
  //            ss1 @1792 (1024), ss2 @2816 (512), ss3 @3328 (256)
  half_t* W1h = (half_t*)d_out;                  // 512*384  = 196608 halfs
  half_t* W2h = W1h + 196608;                    // 256*512  = 131072 halfs
  half_t* W3h = W1h + 327680;                    // 128*256  =  32768 halfs

  prep_kernel<<<417, 256, 0, stream>>>(x_points, xq, W1, W2, W3, W1h, st);
  interp_kernel<<<512, 1024, 0, stream>>>(y_points, y_feats, x_feats, xq, A0);

  // gemm1: 256x128 tile, 1024 blocks (XCD-swizzled, n-fastest), pipelined
  gemm256p<384, 512, 4, false><<<1024, 512, 0, stream>>>(A0, W1h, b1, z1, st + 0, nullptr);
  finalize_kernel<<<1, 512, 0, stream>>>(st + 0, g1, be1, st + 1792, 512);

  // gemm2: BN1+ReLU fused into A-staging, pipelined
  gemm256p<512, 256, 2, true><<<512, 512, 0, stream>>>(z1, W2h, b2, z2, st + 1024, st + 1792);
  finalize_kernel<<<1, 256, 0, stream>>>(st + 1024, g2, be2, st + 2816, 256);

  // gemm3: BN2+ReLU fused, pipelined, TOUT layout
  gemm128p<256, 128, true, true><<<dim3(512, 1), 256, 0, stream>>>(z2, W3h, b3, z3T, st + 1536, st + 2816);
  finalize_kernel<<<1, 128, 0, stream>>>(st + 1536, g3, be3, st + 3328, 128);

  // final: elementwise BN3+ReLU fp16->fp32 (no transpose needed)
  bnfin_kernel<<<4096, 256, 0, stream>>>(z3T, st + 3328, (float*)d_out);
}